// Round 9
// baseline (250.149 us; speedup 1.0000x reference)
//
#include <hip/hip_runtime.h>

// GCN decoder: 2x GCNConv (self-loops, symmetric norm) + FC to 1024.
// n = 50000 nodes, E = 800000 directed edges, feats 64 -> 64 -> 32 -> 1024.
// Round 9: single-kernel decoupled-lookback scan (merges scan1+scan3);
//          agg32 fused into FC (gather 64 rows -> LDS -> register-blocked FC);
//          dispatches 10 -> 8.

#define TB 256
#define SCHUNK 4096        // scan elements per block (1024 thr x 4)
#define FLAGB (1 << 30)    // scan "total published" flag bit (totals < 2^20)

typedef __attribute__((ext_vector_type(4))) float f32x4;

// ---- utility ------------------------------------------------------------

__global__ void k_zero(int4* __restrict__ p, int n4) {
    int i = blockIdx.x * TB + threadIdx.x;
    if (i < n4) p[i] = make_int4(0, 0, 0, 0);
}

// ---- CSR build ----------------------------------------------------------

// Count in-degree; record each edge's slot within its dst list.
__global__ void k_hist(const int* __restrict__ dst, int* __restrict__ cnt,
                       int* __restrict__ slot, int E) {
    int e = blockIdx.x * TB + threadIdx.x;
    if (e < E) slot[e] = atomicAdd(&cnt[dst[e]], 1);
}

// Exclusive scan of cnt -> off (+ fused dinv), one kernel via decoupled
// lookback. nChunks (<=13) blocks are trivially co-resident, so the spin on
// predecessors' published totals cannot deadlock regardless of dispatch order.
__global__ __launch_bounds__(1024)
void k_scanLB(const int* __restrict__ cnt, int* __restrict__ off,
              float* __restrict__ dinv, int* __restrict__ work, int n, int E) {
    __shared__ int wsum[16];
    __shared__ int pfx_s;
    int b = blockIdx.x;
    int i4 = b * SCHUNK + threadIdx.x * 4;
    int lane = threadIdx.x & 63, wid = threadIdx.x >> 6;
    int v0 = 0, v1 = 0, v2 = 0, v3 = 0;
    if (i4 + 3 < n) {
        int4 t = *(const int4*)(cnt + i4);
        v0 = t.x; v1 = t.y; v2 = t.z; v3 = t.w;
    } else {
        if (i4 < n) v0 = cnt[i4];
        if (i4 + 1 < n) v1 = cnt[i4 + 1];
        if (i4 + 2 < n) v2 = cnt[i4 + 2];
        if (i4 + 3 < n) v3 = cnt[i4 + 3];
    }
    // dinv needs no prefix -- store immediately (overlaps the lookback)
    if (i4 < n)     dinv[i4]     = rsqrtf((float)(v0 + 1));
    if (i4 + 1 < n) dinv[i4 + 1] = rsqrtf((float)(v1 + 1));
    if (i4 + 2 < n) dinv[i4 + 2] = rsqrtf((float)(v2 + 1));
    if (i4 + 3 < n) dinv[i4 + 3] = rsqrtf((float)(v3 + 1));

    int s = v0 + v1 + v2 + v3;
    int x = s;
#pragma unroll
    for (int ofs = 1; ofs < 64; ofs <<= 1) {
        int t = __shfl_up(x, ofs, 64);
        if (lane >= ofs) x += t;
    }
    if (lane == 63) wsum[wid] = x;
    __syncthreads();
    int wp = 0;
#pragma unroll
    for (int wv = 0; wv < 16; ++wv) wp += (wv < wid) ? wsum[wv] : 0;
    int excl = wp + x - s;

    if (threadIdx.x == 0) {
        int tot = 0;
#pragma unroll
        for (int wv = 0; wv < 16; ++wv) tot += wsum[wv];
        atomicOr(&work[b], tot | FLAGB);         // publish own total first
        int pfx = 0;
        for (int j = 0; j < b; ++j) {            // then wait on predecessors
            int v;
            do { v = atomicOr(&work[j], 0); } while (!(v & FLAGB));
            pfx += v & (FLAGB - 1);
        }
        pfx_s = pfx;
        if (b == 0) off[n] = E;
    }
    __syncthreads();
    excl += pfx_s;
    if (i4 < n)     off[i4]     = excl;
    if (i4 + 1 < n) off[i4 + 1] = excl + v0;
    if (i4 + 2 < n) off[i4 + 2] = excl + v0 + v1;
    if (i4 + 3 < n) off[i4 + 3] = excl + v0 + v1 + v2;
}

// Atomic-free fill: position = off[dst] + slot (recorded by hist).
__global__ void k_fill(const int* __restrict__ src, const int* __restrict__ dst,
                       const int* __restrict__ off, const int* __restrict__ slot,
                       int* __restrict__ eSrc, int E) {
    int e = blockIdx.x * TB + threadIdx.x;
    if (e >= E) return;
    eSrc[off[dst[e]] + slot[e]] = src[e];
}

// ---- dense GEMMs (epilogue scales row by dinv[r]) -----------------------

__global__ void k_gemm_x64(const float* __restrict__ X, const float* __restrict__ W,
                           const float* __restrict__ dinv, float* __restrict__ Y, int n) {
    __shared__ float Ws[64 * 64];
    __shared__ float Xs[16 * 64];
    for (int i = threadIdx.x; i < 64 * 64; i += TB) Ws[i] = W[i];
    int r0 = blockIdx.x * 16;
    int rows = min(16, n - r0);
    {
        const float4* Xg = (const float4*)(X + (size_t)r0 * 64);
        float4* Xs4 = (float4*)Xs;
        int tot4 = rows * 16;
        for (int i = threadIdx.x; i < tot4; i += TB) Xs4[i] = Xg[i];
    }
    __syncthreads();
    int c = threadIdx.x & 63;
    int g = threadIdx.x >> 6;  // 0..3
#pragma unroll
    for (int rr = 0; rr < 4; ++rr) {
        int rb = g + rr * 4;
        int r = r0 + rb;
        if (r >= n) break;
        const float* x = Xs + rb * 64;
        float acc = 0.f;
#pragma unroll
        for (int k = 0; k < 64; ++k) acc = fmaf(x[k], Ws[k * 64 + c], acc);
        Y[(size_t)r * 64 + c] = acc * dinv[r];
    }
}

__global__ void k_gemm_64_32(const float* __restrict__ X, const float* __restrict__ W,
                             const float* __restrict__ dinv, float* __restrict__ Y, int n) {
    __shared__ float Ws[64 * 32];
    __shared__ float Xs[32 * 64];
    for (int i = threadIdx.x; i < 64 * 32; i += TB) Ws[i] = W[i];
    int r0 = blockIdx.x * 32;
    int rows = min(32, n - r0);
    {
        const float4* Xg = (const float4*)(X + (size_t)r0 * 64);
        float4* Xs4 = (float4*)Xs;
        int tot4 = rows * 16;
        for (int i = threadIdx.x; i < tot4; i += TB) Xs4[i] = Xg[i];
    }
    __syncthreads();
    int c = threadIdx.x & 31;
    int g = threadIdx.x >> 5;  // 0..7
#pragma unroll
    for (int rr = 0; rr < 4; ++rr) {
        int rb = g + rr * 8;
        int r = r0 + rb;
        if (r >= n) break;
        const float* x = Xs + rb * 64;
        float acc = 0.f;
#pragma unroll
        for (int k = 0; k < 64; ++k) acc = fmaf(x[k], Ws[k * 32 + c], acc);
        Y[(size_t)r * 32 + c] = acc * dinv[r];
    }
}

// ---- conv1 aggregation (pre-scaled H'), 64 feats -------------------------
// out[i] = relu( (sum_{s in N(i)} H'[s] + H'[i]) * dinv[i] + b )
// wave per node; lane = (slot 0..7, feat4 0..7); 2 gathers/lane.

__global__ void k_agg64(const float4* __restrict__ H4, const int* __restrict__ off,
                        const int* __restrict__ eSrc, const float* __restrict__ dinv,
                        const float4* __restrict__ b4, float4* __restrict__ out4, int n) {
    int node = blockIdx.x * 4 + (threadIdx.x >> 6);
    if (node >= n) return;
    int lane = threadIdx.x & 63;
    int feat4 = lane & 7;
    int slot = lane >> 3;
    int j0 = off[node], j1 = off[node + 1];
    float4 lo = make_float4(0.f, 0.f, 0.f, 0.f);
    float4 hi = make_float4(0.f, 0.f, 0.f, 0.f);
    for (int e = j0 + slot; e < j1; e += 8) {
        int s = eSrc[e];
        float4 a = H4[(size_t)s * 16 + feat4];
        float4 b = H4[(size_t)s * 16 + 8 + feat4];
        lo.x += a.x; lo.y += a.y; lo.z += a.z; lo.w += a.w;
        hi.x += b.x; hi.y += b.y; hi.z += b.z; hi.w += b.w;
    }
#pragma unroll
    for (int ofs = 8; ofs < 64; ofs <<= 1) {
        lo.x += __shfl_xor(lo.x, ofs, 64);
        lo.y += __shfl_xor(lo.y, ofs, 64);
        lo.z += __shfl_xor(lo.z, ofs, 64);
        lo.w += __shfl_xor(lo.w, ofs, 64);
        hi.x += __shfl_xor(hi.x, ofs, 64);
        hi.y += __shfl_xor(hi.y, ofs, 64);
        hi.z += __shfl_xor(hi.z, ofs, 64);
        hi.w += __shfl_xor(hi.w, ofs, 64);
    }
    if (slot == 0) {
        float dv = dinv[node];
        float4 s0 = H4[(size_t)node * 16 + feat4];
        float4 s1 = H4[(size_t)node * 16 + 8 + feat4];
        float4 c0 = b4[feat4];
        float4 c1 = b4[feat4 + 8];
        float4 r0, r1;
        r0.x = fmaxf(fmaf(lo.x + s0.x, dv, c0.x), 0.f);
        r0.y = fmaxf(fmaf(lo.y + s0.y, dv, c0.y), 0.f);
        r0.z = fmaxf(fmaf(lo.z + s0.z, dv, c0.z), 0.f);
        r0.w = fmaxf(fmaf(lo.w + s0.w, dv, c0.w), 0.f);
        r1.x = fmaxf(fmaf(hi.x + s1.x, dv, c1.x), 0.f);
        r1.y = fmaxf(fmaf(hi.y + s1.y, dv, c1.y), 0.f);
        r1.z = fmaxf(fmaf(hi.z + s1.z, dv, c1.z), 0.f);
        r1.w = fmaxf(fmaf(hi.w + s1.w, dv, c1.w), 0.f);
        out4[(size_t)node * 16 + feat4] = r0;
        out4[(size_t)node * 16 + 8 + feat4] = r1;
    }
}

// ---- fused conv2-aggregation + FC ----------------------------------------
// Phase A: each wave aggregates 16 nodes (slot 0..15, feat4 0..3 layout,
//          as the former k_agg32) into Xs[64][32] (+dinv, +b2, no relu).
// Phase B: register-blocked FC (thread owns 4 adjacent W cols, 128 VGPRs),
//          f32x4 nontemporal stores of the 204.8 MB output.
__global__ __launch_bounds__(TB, 2)
void k_aggfc(const float4* __restrict__ H4, const int* __restrict__ off,
             const int* __restrict__ eSrc, const float* __restrict__ dinv,
             const float4* __restrict__ b4, const float* __restrict__ Wfc,
             const float* __restrict__ bfc, float* __restrict__ Y, int n) {
    __shared__ float Xs[64 * 32];
    int r0 = blockIdx.x * 64;
    int c0 = threadIdx.x * 4;  // 256 threads x 4 = 1024 cols

    // W loads issued up front; latency hidden under the gather phase.
    float4 w[32];
#pragma unroll
    for (int k = 0; k < 32; ++k) w[k] = *(const float4*)(Wfc + k * 1024 + c0);
    float4 bb = *(const float4*)(bfc + c0);

    // ---- phase A: aggregate 64 rows into LDS ----
    int wv = threadIdx.x >> 6;
    int lane = threadIdx.x & 63;
    int feat4 = lane & 3;
    int slot = lane >> 2;
    for (int i = 0; i < 16; ++i) {
        int node = r0 + wv * 16 + i;
        if (node >= n) break;
        int j0 = off[node], j1 = off[node + 1];
        float4 lo = make_float4(0.f, 0.f, 0.f, 0.f);
        float4 hi = make_float4(0.f, 0.f, 0.f, 0.f);
        for (int e = j0 + slot; e < j1; e += 16) {
            int s = eSrc[e];
            float4 a = H4[(size_t)s * 8 + feat4];
            float4 b = H4[(size_t)s * 8 + 4 + feat4];
            lo.x += a.x; lo.y += a.y; lo.z += a.z; lo.w += a.w;
            hi.x += b.x; hi.y += b.y; hi.z += b.z; hi.w += b.w;
        }
#pragma unroll
        for (int ofs = 4; ofs < 64; ofs <<= 1) {
            lo.x += __shfl_xor(lo.x, ofs, 64);
            lo.y += __shfl_xor(lo.y, ofs, 64);
            lo.z += __shfl_xor(lo.z, ofs, 64);
            lo.w += __shfl_xor(lo.w, ofs, 64);
            hi.x += __shfl_xor(hi.x, ofs, 64);
            hi.y += __shfl_xor(hi.y, ofs, 64);
            hi.z += __shfl_xor(hi.z, ofs, 64);
            hi.w += __shfl_xor(hi.w, ofs, 64);
        }
        if (slot == 0) {
            float dv = dinv[node];
            float4 s0 = H4[(size_t)node * 8 + feat4];
            float4 s1 = H4[(size_t)node * 8 + 4 + feat4];
            float4 c0b = b4[feat4];
            float4 c1b = b4[feat4 + 4];
            float4 q0, q1;
            q0.x = fmaf(lo.x + s0.x, dv, c0b.x);
            q0.y = fmaf(lo.y + s0.y, dv, c0b.y);
            q0.z = fmaf(lo.z + s0.z, dv, c0b.z);
            q0.w = fmaf(lo.w + s0.w, dv, c0b.w);
            q1.x = fmaf(hi.x + s1.x, dv, c1b.x);
            q1.y = fmaf(hi.y + s1.y, dv, c1b.y);
            q1.z = fmaf(hi.z + s1.z, dv, c1b.z);
            q1.w = fmaf(hi.w + s1.w, dv, c1b.w);
            float4* row = (float4*)(Xs + (size_t)(node - r0) * 32);
            row[feat4] = q0;
            row[feat4 + 4] = q1;
        }
    }
    __syncthreads();

    // ---- phase B: FC on the 64 LDS rows ----
    int rows = min(64, n - r0);
    for (int r = 0; r < rows; ++r) {
        const float* x = Xs + r * 32;
        float a0 = bb.x, a1 = bb.y, a2 = bb.z, a3 = bb.w;
#pragma unroll
        for (int k = 0; k < 32; ++k) {
            float xv = x[k];
            a0 = fmaf(xv, w[k].x, a0);
            a1 = fmaf(xv, w[k].y, a1);
            a2 = fmaf(xv, w[k].z, a2);
            a3 = fmaf(xv, w[k].w, a3);
        }
        f32x4 v;
        v.x = a0; v.y = a1; v.z = a2; v.w = a3;
        __builtin_nontemporal_store(v, (f32x4*)(Y + (size_t)(r0 + r) * 1024 + c0));
    }
}

// ---- launch -------------------------------------------------------------

extern "C" void kernel_launch(void* const* d_in, const int* in_sizes, int n_in,
                              void* d_out, int out_size, void* d_ws, size_t ws_size,
                              hipStream_t stream) {
    const float* z   = (const float*)d_in[0];
    const int*   ei  = (const int*)d_in[1];
    const float* W1  = (const float*)d_in[2];
    const float* b1  = (const float*)d_in[3];
    const float* W2  = (const float*)d_in[4];
    const float* b2  = (const float*)d_in[5];
    const float* Wfc = (const float*)d_in[6];
    const float* bfc = (const float*)d_in[7];
    float* out = (float*)d_out;

    int n = in_sizes[0] / 64;
    int E = in_sizes[1] / 2;
    const int* src = ei;
    const int* dst = ei + E;

    // Workspace layout (4-byte words):
    //   cnt[nPad] | work[16] | off[n+1] | slot[E] | eSrc[E] | dinv[n] | bufA[n*64] | bufB[n*64]
    int nPad = (n + 3) & ~3;
    int* cnt    = (int*)d_ws;
    int* work   = cnt + nPad;
    int* off    = work + 16;
    int* slot   = off + (n + 1);
    int* eSrc   = slot + E;
    float* dinv = (float*)(eSrc + E);
    float* bufA = dinv + n;
    float* bufB = bufA + (size_t)n * 64;
    float* h2   = bufA;

    int nChunks = (n + SCHUNK - 1) / SCHUNK;

    // ---- CSR build + norms (4 dispatches) ----
    {
        int n4 = (nPad + 16) / 4;  // zero cnt + work together
        k_zero<<<(n4 + TB - 1) / TB, TB, 0, stream>>>((int4*)cnt, n4);
    }
    k_hist<<<(E + TB - 1) / TB, TB, 0, stream>>>(dst, cnt, slot, E);
    k_scanLB<<<nChunks, 1024, 0, stream>>>(cnt, off, dinv, work, n, E);
    k_fill<<<(E + TB - 1) / TB, TB, 0, stream>>>(src, dst, off, slot, eSrc, E);

    // ---- conv1: h1' = dinv .* (z @ W1) ; gather-agg (+b1, relu) -> bufB ----
    k_gemm_x64<<<(n + 15) / 16, TB, 0, stream>>>(z, W1, dinv, bufA, n);
    k_agg64<<<(n + 3) / 4, TB, 0, stream>>>((const float4*)bufA, off, eSrc, dinv,
                                            (const float4*)b1, (float4*)bufB, n);

    // ---- conv2 GEMM: h2' = dinv .* (bufB @ W2) -> bufA ----
    k_gemm_64_32<<<(n + 31) / 32, TB, 0, stream>>>(bufB, W2, dinv, h2, n);

    // ---- fused conv2-agg + FC -> out ----
    k_aggfc<<<(n + 63) / 64, TB, 0, stream>>>((const float4*)h2, off, eSrc, dinv,
                                              (const float4*)b2, Wfc, bfc, out, n);
}

// Round 10
// 227.332 us; speedup vs baseline: 1.1004x; 1.1004x over previous
//
#include <hip/hip_runtime.h>

// GCN decoder: 2x GCNConv (self-loops, symmetric norm) + FC to 1024.
// n = 50000 nodes, E = 800000 directed edges, feats 64 -> 64 -> 32 -> 1024.
// Round 10: revert round-9's agg+FC fusion (occupancy loss in gather phase);
//           keep lookback scan; union-dispatch fill+gemm1 (independent after
//           scanLB) -> 8 dispatches with round-8 per-kernel geometry.

#define TB 256
#define FC_ROWS 64
#define SCHUNK 4096        // scan elements per block (1024 thr x 4)
#define FLAGB (1 << 30)    // scan "total published" flag bit (totals < 2^20)

typedef __attribute__((ext_vector_type(4))) float f32x4;

// ---- utility ------------------------------------------------------------

__global__ void k_zero(int4* __restrict__ p, int n4) {
    int i = blockIdx.x * TB + threadIdx.x;
    if (i < n4) p[i] = make_int4(0, 0, 0, 0);
}

// ---- CSR build ----------------------------------------------------------

// Count in-degree; record each edge's slot within its dst list.
__global__ void k_hist(const int* __restrict__ dst, int* __restrict__ cnt,
                       int* __restrict__ slot, int E) {
    int e = blockIdx.x * TB + threadIdx.x;
    if (e < E) slot[e] = atomicAdd(&cnt[dst[e]], 1);
}

// Exclusive scan of cnt -> off (+ fused dinv), one kernel via decoupled
// lookback. nChunks (<=13) blocks are trivially co-resident, so the spin on
// predecessors' published totals cannot deadlock regardless of dispatch order.
__global__ __launch_bounds__(1024)
void k_scanLB(const int* __restrict__ cnt, int* __restrict__ off,
              float* __restrict__ dinv, int* __restrict__ work, int n, int E) {
    __shared__ int wsum[16];
    __shared__ int pfx_s;
    int b = blockIdx.x;
    int i4 = b * SCHUNK + threadIdx.x * 4;
    int lane = threadIdx.x & 63, wid = threadIdx.x >> 6;
    int v0 = 0, v1 = 0, v2 = 0, v3 = 0;
    if (i4 + 3 < n) {
        int4 t = *(const int4*)(cnt + i4);
        v0 = t.x; v1 = t.y; v2 = t.z; v3 = t.w;
    } else {
        if (i4 < n) v0 = cnt[i4];
        if (i4 + 1 < n) v1 = cnt[i4 + 1];
        if (i4 + 2 < n) v2 = cnt[i4 + 2];
        if (i4 + 3 < n) v3 = cnt[i4 + 3];
    }
    // dinv needs no prefix -- store immediately (overlaps the lookback)
    if (i4 < n)     dinv[i4]     = rsqrtf((float)(v0 + 1));
    if (i4 + 1 < n) dinv[i4 + 1] = rsqrtf((float)(v1 + 1));
    if (i4 + 2 < n) dinv[i4 + 2] = rsqrtf((float)(v2 + 1));
    if (i4 + 3 < n) dinv[i4 + 3] = rsqrtf((float)(v3 + 1));

    int s = v0 + v1 + v2 + v3;
    int x = s;
#pragma unroll
    for (int ofs = 1; ofs < 64; ofs <<= 1) {
        int t = __shfl_up(x, ofs, 64);
        if (lane >= ofs) x += t;
    }
    if (lane == 63) wsum[wid] = x;
    __syncthreads();
    int wp = 0;
#pragma unroll
    for (int wv = 0; wv < 16; ++wv) wp += (wv < wid) ? wsum[wv] : 0;
    int excl = wp + x - s;

    if (threadIdx.x == 0) {
        int tot = 0;
#pragma unroll
        for (int wv = 0; wv < 16; ++wv) tot += wsum[wv];
        atomicOr(&work[b], tot | FLAGB);         // publish own total first
        int pfx = 0;
        for (int j = 0; j < b; ++j) {            // then wait on predecessors
            int v;
            do { v = atomicOr(&work[j], 0); } while (!(v & FLAGB));
            pfx += v & (FLAGB - 1);
        }
        pfx_s = pfx;
        if (b == 0) off[n] = E;
    }
    __syncthreads();
    excl += pfx_s;
    if (i4 < n)     off[i4]     = excl;
    if (i4 + 1 < n) off[i4 + 1] = excl + v0;
    if (i4 + 2 < n) off[i4 + 2] = excl + v0 + v1;
    if (i4 + 3 < n) off[i4 + 3] = excl + v0 + v1 + v2;
}

// ---- union dispatch: CSR fill (blocks [0,fillBlocks)) + conv1 GEMM -------
// Both depend only on scanLB; block-granular branch, no divergent syncs
// (fill blocks return before the gemm branch's __syncthreads).
// fill: eSrc[off[dst]+slot] = src (atomic-free).
// gemm: Y[r,c] = dinv[r] * sum_k X[r,k] W[k,c]; 64x64 W + 16 X rows in LDS.
__global__ void k_fill_gemm(const int* __restrict__ src, const int* __restrict__ dst,
                            const int* __restrict__ off, const int* __restrict__ slot,
                            int* __restrict__ eSrc, int E, int fillBlocks,
                            const float* __restrict__ X, const float* __restrict__ W,
                            const float* __restrict__ dinv, float* __restrict__ Y, int n) {
    __shared__ float Ws[64 * 64];
    __shared__ float Xs[16 * 64];
    if ((int)blockIdx.x < fillBlocks) {
        int e = blockIdx.x * TB + threadIdx.x;
        if (e < E) eSrc[off[dst[e]] + slot[e]] = src[e];
        return;
    }
    int gb = blockIdx.x - fillBlocks;
    for (int i = threadIdx.x; i < 64 * 64; i += TB) Ws[i] = W[i];
    int r0 = gb * 16;
    int rows = min(16, n - r0);
    {
        const float4* Xg = (const float4*)(X + (size_t)r0 * 64);
        float4* Xs4 = (float4*)Xs;
        int tot4 = rows * 16;
        for (int i = threadIdx.x; i < tot4; i += TB) Xs4[i] = Xg[i];
    }
    __syncthreads();
    int c = threadIdx.x & 63;
    int g = threadIdx.x >> 6;  // 0..3
#pragma unroll
    for (int rr = 0; rr < 4; ++rr) {
        int rb = g + rr * 4;
        int r = r0 + rb;
        if (r >= n) break;
        const float* x = Xs + rb * 64;
        float acc = 0.f;
#pragma unroll
        for (int k = 0; k < 64; ++k) acc = fmaf(x[k], Ws[k * 64 + c], acc);
        Y[(size_t)r * 64 + c] = acc * dinv[r];
    }
}

// ---- conv2 GEMM (epilogue scales row by dinv[r]) -------------------------

__global__ void k_gemm_64_32(const float* __restrict__ X, const float* __restrict__ W,
                             const float* __restrict__ dinv, float* __restrict__ Y, int n) {
    __shared__ float Ws[64 * 32];
    __shared__ float Xs[32 * 64];
    for (int i = threadIdx.x; i < 64 * 32; i += TB) Ws[i] = W[i];
    int r0 = blockIdx.x * 32;
    int rows = min(32, n - r0);
    {
        const float4* Xg = (const float4*)(X + (size_t)r0 * 64);
        float4* Xs4 = (float4*)Xs;
        int tot4 = rows * 16;
        for (int i = threadIdx.x; i < tot4; i += TB) Xs4[i] = Xg[i];
    }
    __syncthreads();
    int c = threadIdx.x & 31;
    int g = threadIdx.x >> 5;  // 0..7
#pragma unroll
    for (int rr = 0; rr < 4; ++rr) {
        int rb = g + rr * 8;
        int r = r0 + rb;
        if (r >= n) break;
        const float* x = Xs + rb * 64;
        float acc = 0.f;
#pragma unroll
        for (int k = 0; k < 64; ++k) acc = fmaf(x[k], Ws[k * 32 + c], acc);
        Y[(size_t)r * 32 + c] = acc * dinv[r];
    }
}

// ---- gather aggregation on pre-scaled H' (= dinv .* H) -------------------
// out[i] = relu?( (sum_{s in N(i)} H'[s] + H'[i]) * dinv[i] + b )
// agg64: wave per node; lane = (slot 0..7, feat4 0..7); 2 gathers/lane.

__global__ void k_agg64(const float4* __restrict__ H4, const int* __restrict__ off,
                        const int* __restrict__ eSrc, const float* __restrict__ dinv,
                        const float4* __restrict__ b4, float4* __restrict__ out4, int n) {
    int node = blockIdx.x * 4 + (threadIdx.x >> 6);
    if (node >= n) return;
    int lane = threadIdx.x & 63;
    int feat4 = lane & 7;
    int slot = lane >> 3;
    int j0 = off[node], j1 = off[node + 1];
    float4 lo = make_float4(0.f, 0.f, 0.f, 0.f);
    float4 hi = make_float4(0.f, 0.f, 0.f, 0.f);
    for (int e = j0 + slot; e < j1; e += 8) {
        int s = eSrc[e];
        float4 a = H4[(size_t)s * 16 + feat4];
        float4 b = H4[(size_t)s * 16 + 8 + feat4];
        lo.x += a.x; lo.y += a.y; lo.z += a.z; lo.w += a.w;
        hi.x += b.x; hi.y += b.y; hi.z += b.z; hi.w += b.w;
    }
#pragma unroll
    for (int ofs = 8; ofs < 64; ofs <<= 1) {
        lo.x += __shfl_xor(lo.x, ofs, 64);
        lo.y += __shfl_xor(lo.y, ofs, 64);
        lo.z += __shfl_xor(lo.z, ofs, 64);
        lo.w += __shfl_xor(lo.w, ofs, 64);
        hi.x += __shfl_xor(hi.x, ofs, 64);
        hi.y += __shfl_xor(hi.y, ofs, 64);
        hi.z += __shfl_xor(hi.z, ofs, 64);
        hi.w += __shfl_xor(hi.w, ofs, 64);
    }
    if (slot == 0) {
        float dv = dinv[node];
        float4 s0 = H4[(size_t)node * 16 + feat4];
        float4 s1 = H4[(size_t)node * 16 + 8 + feat4];
        float4 c0 = b4[feat4];
        float4 c1 = b4[feat4 + 8];
        float4 r0, r1;
        r0.x = fmaxf(fmaf(lo.x + s0.x, dv, c0.x), 0.f);
        r0.y = fmaxf(fmaf(lo.y + s0.y, dv, c0.y), 0.f);
        r0.z = fmaxf(fmaf(lo.z + s0.z, dv, c0.z), 0.f);
        r0.w = fmaxf(fmaf(lo.w + s0.w, dv, c0.w), 0.f);
        r1.x = fmaxf(fmaf(hi.x + s1.x, dv, c1.x), 0.f);
        r1.y = fmaxf(fmaf(hi.y + s1.y, dv, c1.y), 0.f);
        r1.z = fmaxf(fmaf(hi.z + s1.z, dv, c1.z), 0.f);
        r1.w = fmaxf(fmaf(hi.w + s1.w, dv, c1.w), 0.f);
        out4[(size_t)node * 16 + feat4] = r0;
        out4[(size_t)node * 16 + 8 + feat4] = r1;
    }
}

// agg32: wave per node; lane = (slot 0..15, feat4 0..3); 2 gathers/lane.
__global__ void k_agg32(const float4* __restrict__ H4, const int* __restrict__ off,
                        const int* __restrict__ eSrc, const float* __restrict__ dinv,
                        const float4* __restrict__ b4, float4* __restrict__ out4, int n) {
    int node = blockIdx.x * 4 + (threadIdx.x >> 6);
    if (node >= n) return;
    int lane = threadIdx.x & 63;
    int feat4 = lane & 3;
    int slot = lane >> 2;
    int j0 = off[node], j1 = off[node + 1];
    float4 lo = make_float4(0.f, 0.f, 0.f, 0.f);
    float4 hi = make_float4(0.f, 0.f, 0.f, 0.f);
    for (int e = j0 + slot; e < j1; e += 16) {
        int s = eSrc[e];
        float4 a = H4[(size_t)s * 8 + feat4];
        float4 b = H4[(size_t)s * 8 + 4 + feat4];
        lo.x += a.x; lo.y += a.y; lo.z += a.z; lo.w += a.w;
        hi.x += b.x; hi.y += b.y; hi.z += b.z; hi.w += b.w;
    }
#pragma unroll
    for (int ofs = 4; ofs < 64; ofs <<= 1) {
        lo.x += __shfl_xor(lo.x, ofs, 64);
        lo.y += __shfl_xor(lo.y, ofs, 64);
        lo.z += __shfl_xor(lo.z, ofs, 64);
        lo.w += __shfl_xor(lo.w, ofs, 64);
        hi.x += __shfl_xor(hi.x, ofs, 64);
        hi.y += __shfl_xor(hi.y, ofs, 64);
        hi.z += __shfl_xor(hi.z, ofs, 64);
        hi.w += __shfl_xor(hi.w, ofs, 64);
    }
    if (slot == 0) {
        float dv = dinv[node];
        float4 s0 = H4[(size_t)node * 8 + feat4];
        float4 s1 = H4[(size_t)node * 8 + 4 + feat4];
        float4 c0 = b4[feat4];
        float4 c1 = b4[feat4 + 4];
        float4 r0, r1;
        r0.x = fmaf(lo.x + s0.x, dv, c0.x);
        r0.y = fmaf(lo.y + s0.y, dv, c0.y);
        r0.z = fmaf(lo.z + s0.z, dv, c0.z);
        r0.w = fmaf(lo.w + s0.w, dv, c0.w);
        r1.x = fmaf(hi.x + s1.x, dv, c1.x);
        r1.y = fmaf(hi.y + s1.y, dv, c1.y);
        r1.z = fmaf(hi.z + s1.z, dv, c1.z);
        r1.w = fmaf(hi.w + s1.w, dv, c1.w);
        out4[(size_t)node * 8 + feat4] = r0;
        out4[(size_t)node * 8 + 4 + feat4] = r1;
    }
}

// ---- FC: Y[n,1024] = X[n,32] @ W[32,1024] + bias ------------------------
// Thread owns 4 adjacent W columns (128 VGPRs of weights); f32x4 nt stores.
__global__ __launch_bounds__(TB, 2)
void k_fc2(const float* __restrict__ X, const float* __restrict__ W,
           const float* __restrict__ bias, float* __restrict__ Y, int n) {
    __shared__ float Xs[FC_ROWS * 32];
    int c0 = threadIdx.x * 4;  // 256 threads x 4 = 1024 cols
    int r0 = blockIdx.x * FC_ROWS;
    int rows = min(FC_ROWS, n - r0);

    float4 w[32];
#pragma unroll
    for (int k = 0; k < 32; ++k) w[k] = *(const float4*)(W + k * 1024 + c0);
    float4 bb = *(const float4*)(bias + c0);

    {
        const float4* Xg = (const float4*)(X + (size_t)r0 * 32);
        float4* Xs4 = (float4*)Xs;
        int tot4 = rows * 8;
        for (int i = threadIdx.x; i < tot4; i += TB) Xs4[i] = Xg[i];
    }
    __syncthreads();

    for (int r = 0; r < rows; ++r) {
        const float* x = Xs + r * 32;
        float a0 = bb.x, a1 = bb.y, a2 = bb.z, a3 = bb.w;
#pragma unroll
        for (int k = 0; k < 32; ++k) {
            float xv = x[k];
            a0 = fmaf(xv, w[k].x, a0);
            a1 = fmaf(xv, w[k].y, a1);
            a2 = fmaf(xv, w[k].z, a2);
            a3 = fmaf(xv, w[k].w, a3);
        }
        f32x4 v;
        v.x = a0; v.y = a1; v.z = a2; v.w = a3;
        __builtin_nontemporal_store(v, (f32x4*)(Y + (size_t)(r0 + r) * 1024 + c0));
    }
}

// ---- launch -------------------------------------------------------------

extern "C" void kernel_launch(void* const* d_in, const int* in_sizes, int n_in,
                              void* d_out, int out_size, void* d_ws, size_t ws_size,
                              hipStream_t stream) {
    const float* z   = (const float*)d_in[0];
    const int*   ei  = (const int*)d_in[1];
    const float* W1  = (const float*)d_in[2];
    const float* b1  = (const float*)d_in[3];
    const float* W2  = (const float*)d_in[4];
    const float* b2  = (const float*)d_in[5];
    const float* Wfc = (const float*)d_in[6];
    const float* bfc = (const float*)d_in[7];
    float* out = (float*)d_out;

    int n = in_sizes[0] / 64;
    int E = in_sizes[1] / 2;
    const int* src = ei;
    const int* dst = ei + E;

    // Workspace layout (4-byte words):
    //   cnt[nPad] | work[16] | off[n+1] | slot[E] | eSrc[E] | dinv[n] | bufA[n*64] | bufB[n*64]
    int nPad = (n + 3) & ~3;
    int* cnt    = (int*)d_ws;
    int* work   = cnt + nPad;
    int* off    = work + 16;
    int* slot   = off + (n + 1);
    int* eSrc   = slot + E;
    float* dinv = (float*)(eSrc + E);
    float* bufA = dinv + n;
    float* bufB = bufA + (size_t)n * 64;
    float* h2   = bufA;
    float* agg2 = bufA + (size_t)n * 32;

    int nChunks = (n + SCHUNK - 1) / SCHUNK;

    // ---- CSR build + norms ----
    {
        int n4 = (nPad + 16) / 4;  // zero cnt + work together
        k_zero<<<(n4 + TB - 1) / TB, TB, 0, stream>>>((int4*)cnt, n4);
    }
    k_hist<<<(E + TB - 1) / TB, TB, 0, stream>>>(dst, cnt, slot, E);
    k_scanLB<<<nChunks, 1024, 0, stream>>>(cnt, off, dinv, work, n, E);

    // ---- union: CSR fill + conv1 GEMM (both depend only on scanLB) ----
    {
        int fillBlocks = (E + TB - 1) / TB;
        int gemmBlocks = (n + 15) / 16;
        k_fill_gemm<<<fillBlocks + gemmBlocks, TB, 0, stream>>>(
            src, dst, off, slot, eSrc, E, fillBlocks, z, W1, dinv, bufA, n);
    }

    // ---- conv1 agg: gather (+b1, relu) -> bufB ----
    k_agg64<<<(n + 3) / 4, TB, 0, stream>>>((const float4*)bufA, off, eSrc, dinv,
                                            (const float4*)b1, (float4*)bufB, n);

    // ---- conv2: h2' = dinv .* (bufB @ W2) ; gather-agg (+b2) -> agg2 ----
    k_gemm_64_32<<<(n + 31) / 32, TB, 0, stream>>>(bufB, W2, dinv, h2, n);
    k_agg32<<<(n + 3) / 4, TB, 0, stream>>>((const float4*)h2, off, eSrc, dinv,
                                            (const float4*)b2, (float4*)agg2, n);

    // ---- fc: out = agg2 @ Wfc + bfc ----
    k_fc2<<<(n + FC_ROWS - 1) / FC_ROWS, TB, 0, stream>>>(agg2, Wfc, bfc, out, n);
}

// Round 11
// 218.205 us; speedup vs baseline: 1.1464x; 1.0418x over previous
//
#include <hip/hip_runtime.h>

// GCN decoder: 2x GCNConv (self-loops, symmetric norm) + FC to 1024.
// n = 50000 nodes, E = 800000 directed edges, feats 64 -> 64 -> 32 -> 1024.
// Round 11: FC occupancy x2 (2 cols/thread, 32 rows/block, launch_bounds(256,4)
//           -> 16 waves/CU) to overlap the fma chain with the 205 MB store
//           stream. Rest frozen from round 10.

#define TB 256
#define FC_ROWS 32
#define SCHUNK 4096        // scan elements per block (1024 thr x 4)
#define FLAGB (1 << 30)    // scan "total published" flag bit (totals < 2^20)

typedef __attribute__((ext_vector_type(2))) float f32x2;

// ---- utility ------------------------------------------------------------

__global__ void k_zero(int4* __restrict__ p, int n4) {
    int i = blockIdx.x * TB + threadIdx.x;
    if (i < n4) p[i] = make_int4(0, 0, 0, 0);
}

// ---- CSR build ----------------------------------------------------------

// Count in-degree; record each edge's slot within its dst list.
__global__ void k_hist(const int* __restrict__ dst, int* __restrict__ cnt,
                       int* __restrict__ slot, int E) {
    int e = blockIdx.x * TB + threadIdx.x;
    if (e < E) slot[e] = atomicAdd(&cnt[dst[e]], 1);
}

// Exclusive scan of cnt -> off (+ fused dinv), one kernel via decoupled
// lookback. nChunks (<=13) blocks are trivially co-resident, so the spin on
// predecessors' published totals cannot deadlock regardless of dispatch order.
__global__ __launch_bounds__(1024)
void k_scanLB(const int* __restrict__ cnt, int* __restrict__ off,
              float* __restrict__ dinv, int* __restrict__ work, int n, int E) {
    __shared__ int wsum[16];
    __shared__ int pfx_s;
    int b = blockIdx.x;
    int i4 = b * SCHUNK + threadIdx.x * 4;
    int lane = threadIdx.x & 63, wid = threadIdx.x >> 6;
    int v0 = 0, v1 = 0, v2 = 0, v3 = 0;
    if (i4 + 3 < n) {
        int4 t = *(const int4*)(cnt + i4);
        v0 = t.x; v1 = t.y; v2 = t.z; v3 = t.w;
    } else {
        if (i4 < n) v0 = cnt[i4];
        if (i4 + 1 < n) v1 = cnt[i4 + 1];
        if (i4 + 2 < n) v2 = cnt[i4 + 2];
        if (i4 + 3 < n) v3 = cnt[i4 + 3];
    }
    // dinv needs no prefix -- store immediately (overlaps the lookback)
    if (i4 < n)     dinv[i4]     = rsqrtf((float)(v0 + 1));
    if (i4 + 1 < n) dinv[i4 + 1] = rsqrtf((float)(v1 + 1));
    if (i4 + 2 < n) dinv[i4 + 2] = rsqrtf((float)(v2 + 1));
    if (i4 + 3 < n) dinv[i4 + 3] = rsqrtf((float)(v3 + 1));

    int s = v0 + v1 + v2 + v3;
    int x = s;
#pragma unroll
    for (int ofs = 1; ofs < 64; ofs <<= 1) {
        int t = __shfl_up(x, ofs, 64);
        if (lane >= ofs) x += t;
    }
    if (lane == 63) wsum[wid] = x;
    __syncthreads();
    int wp = 0;
#pragma unroll
    for (int wv = 0; wv < 16; ++wv) wp += (wv < wid) ? wsum[wv] : 0;
    int excl = wp + x - s;

    if (threadIdx.x == 0) {
        int tot = 0;
#pragma unroll
        for (int wv = 0; wv < 16; ++wv) tot += wsum[wv];
        atomicOr(&work[b], tot | FLAGB);         // publish own total first
        int pfx = 0;
        for (int j = 0; j < b; ++j) {            // then wait on predecessors
            int v;
            do { v = atomicOr(&work[j], 0); } while (!(v & FLAGB));
            pfx += v & (FLAGB - 1);
        }
        pfx_s = pfx;
        if (b == 0) off[n] = E;
    }
    __syncthreads();
    excl += pfx_s;
    if (i4 < n)     off[i4]     = excl;
    if (i4 + 1 < n) off[i4 + 1] = excl + v0;
    if (i4 + 2 < n) off[i4 + 2] = excl + v0 + v1;
    if (i4 + 3 < n) off[i4 + 3] = excl + v0 + v1 + v2;
}

// ---- union dispatch: CSR fill (blocks [0,fillBlocks)) + conv1 GEMM -------
// Both depend only on scanLB; block-granular branch, no divergent syncs
// (fill blocks return before the gemm branch's __syncthreads).
__global__ void k_fill_gemm(const int* __restrict__ src, const int* __restrict__ dst,
                            const int* __restrict__ off, const int* __restrict__ slot,
                            int* __restrict__ eSrc, int E, int fillBlocks,
                            const float* __restrict__ X, const float* __restrict__ W,
                            const float* __restrict__ dinv, float* __restrict__ Y, int n) {
    __shared__ float Ws[64 * 64];
    __shared__ float Xs[16 * 64];
    if ((int)blockIdx.x < fillBlocks) {
        int e = blockIdx.x * TB + threadIdx.x;
        if (e < E) eSrc[off[dst[e]] + slot[e]] = src[e];
        return;
    }
    int gb = blockIdx.x - fillBlocks;
    for (int i = threadIdx.x; i < 64 * 64; i += TB) Ws[i] = W[i];
    int r0 = gb * 16;
    int rows = min(16, n - r0);
    {
        const float4* Xg = (const float4*)(X + (size_t)r0 * 64);
        float4* Xs4 = (float4*)Xs;
        int tot4 = rows * 16;
        for (int i = threadIdx.x; i < tot4; i += TB) Xs4[i] = Xg[i];
    }
    __syncthreads();
    int c = threadIdx.x & 63;
    int g = threadIdx.x >> 6;  // 0..3
#pragma unroll
    for (int rr = 0; rr < 4; ++rr) {
        int rb = g + rr * 4;
        int r = r0 + rb;
        if (r >= n) break;
        const float* x = Xs + rb * 64;
        float acc = 0.f;
#pragma unroll
        for (int k = 0; k < 64; ++k) acc = fmaf(x[k], Ws[k * 64 + c], acc);
        Y[(size_t)r * 64 + c] = acc * dinv[r];
    }
}

// ---- conv2 GEMM (epilogue scales row by dinv[r]) -------------------------

__global__ void k_gemm_64_32(const float* __restrict__ X, const float* __restrict__ W,
                             const float* __restrict__ dinv, float* __restrict__ Y, int n) {
    __shared__ float Ws[64 * 32];
    __shared__ float Xs[32 * 64];
    for (int i = threadIdx.x; i < 64 * 32; i += TB) Ws[i] = W[i];
    int r0 = blockIdx.x * 32;
    int rows = min(32, n - r0);
    {
        const float4* Xg = (const float4*)(X + (size_t)r0 * 64);
        float4* Xs4 = (float4*)Xs;
        int tot4 = rows * 16;
        for (int i = threadIdx.x; i < tot4; i += TB) Xs4[i] = Xg[i];
    }
    __syncthreads();
    int c = threadIdx.x & 31;
    int g = threadIdx.x >> 5;  // 0..7
#pragma unroll
    for (int rr = 0; rr < 4; ++rr) {
        int rb = g + rr * 8;
        int r = r0 + rb;
        if (r >= n) break;
        const float* x = Xs + rb * 64;
        float acc = 0.f;
#pragma unroll
        for (int k = 0; k < 64; ++k) acc = fmaf(x[k], Ws[k * 32 + c], acc);
        Y[(size_t)r * 32 + c] = acc * dinv[r];
    }
}

// ---- gather aggregation on pre-scaled H' (= dinv .* H) -------------------
// out[i] = relu?( (sum_{s in N(i)} H'[s] + H'[i]) * dinv[i] + b )
// agg64: wave per node; lane = (slot 0..7, feat4 0..7); 2 gathers/lane.

__global__ void k_agg64(const float4* __restrict__ H4, const int* __restrict__ off,
                        const int* __restrict__ eSrc, const float* __restrict__ dinv,
                        const float4* __restrict__ b4, float4* __restrict__ out4, int n) {
    int node = blockIdx.x * 4 + (threadIdx.x >> 6);
    if (node >= n) return;
    int lane = threadIdx.x & 63;
    int feat4 = lane & 7;
    int slot = lane >> 3;
    int j0 = off[node], j1 = off[node + 1];
    float4 lo = make_float4(0.f, 0.f, 0.f, 0.f);
    float4 hi = make_float4(0.f, 0.f, 0.f, 0.f);
    for (int e = j0 + slot; e < j1; e += 8) {
        int s = eSrc[e];
        float4 a = H4[(size_t)s * 16 + feat4];
        float4 b = H4[(size_t)s * 16 + 8 + feat4];
        lo.x += a.x; lo.y += a.y; lo.z += a.z; lo.w += a.w;
        hi.x += b.x; hi.y += b.y; hi.z += b.z; hi.w += b.w;
    }
#pragma unroll
    for (int ofs = 8; ofs < 64; ofs <<= 1) {
        lo.x += __shfl_xor(lo.x, ofs, 64);
        lo.y += __shfl_xor(lo.y, ofs, 64);
        lo.z += __shfl_xor(lo.z, ofs, 64);
        lo.w += __shfl_xor(lo.w, ofs, 64);
        hi.x += __shfl_xor(hi.x, ofs, 64);
        hi.y += __shfl_xor(hi.y, ofs, 64);
        hi.z += __shfl_xor(hi.z, ofs, 64);
        hi.w += __shfl_xor(hi.w, ofs, 64);
    }
    if (slot == 0) {
        float dv = dinv[node];
        float4 s0 = H4[(size_t)node * 16 + feat4];
        float4 s1 = H4[(size_t)node * 16 + 8 + feat4];
        float4 c0 = b4[feat4];
        float4 c1 = b4[feat4 + 8];
        float4 r0, r1;
        r0.x = fmaxf(fmaf(lo.x + s0.x, dv, c0.x), 0.f);
        r0.y = fmaxf(fmaf(lo.y + s0.y, dv, c0.y), 0.f);
        r0.z = fmaxf(fmaf(lo.z + s0.z, dv, c0.z), 0.f);
        r0.w = fmaxf(fmaf(lo.w + s0.w, dv, c0.w), 0.f);
        r1.x = fmaxf(fmaf(hi.x + s1.x, dv, c1.x), 0.f);
        r1.y = fmaxf(fmaf(hi.y + s1.y, dv, c1.y), 0.f);
        r1.z = fmaxf(fmaf(hi.z + s1.z, dv, c1.z), 0.f);
        r1.w = fmaxf(fmaf(hi.w + s1.w, dv, c1.w), 0.f);
        out4[(size_t)node * 16 + feat4] = r0;
        out4[(size_t)node * 16 + 8 + feat4] = r1;
    }
}

// agg32: wave per node; lane = (slot 0..15, feat4 0..3); 2 gathers/lane.
__global__ void k_agg32(const float4* __restrict__ H4, const int* __restrict__ off,
                        const int* __restrict__ eSrc, const float* __restrict__ dinv,
                        const float4* __restrict__ b4, float4* __restrict__ out4, int n) {
    int node = blockIdx.x * 4 + (threadIdx.x >> 6);
    if (node >= n) return;
    int lane = threadIdx.x & 63;
    int feat4 = lane & 3;
    int slot = lane >> 2;
    int j0 = off[node], j1 = off[node + 1];
    float4 lo = make_float4(0.f, 0.f, 0.f, 0.f);
    float4 hi = make_float4(0.f, 0.f, 0.f, 0.f);
    for (int e = j0 + slot; e < j1; e += 16) {
        int s = eSrc[e];
        float4 a = H4[(size_t)s * 8 + feat4];
        float4 b = H4[(size_t)s * 8 + 4 + feat4];
        lo.x += a.x; lo.y += a.y; lo.z += a.z; lo.w += a.w;
        hi.x += b.x; hi.y += b.y; hi.z += b.z; hi.w += b.w;
    }
#pragma unroll
    for (int ofs = 4; ofs < 64; ofs <<= 1) {
        lo.x += __shfl_xor(lo.x, ofs, 64);
        lo.y += __shfl_xor(lo.y, ofs, 64);
        lo.z += __shfl_xor(lo.z, ofs, 64);
        lo.w += __shfl_xor(lo.w, ofs, 64);
        hi.x += __shfl_xor(hi.x, ofs, 64);
        hi.y += __shfl_xor(hi.y, ofs, 64);
        hi.z += __shfl_xor(hi.z, ofs, 64);
        hi.w += __shfl_xor(hi.w, ofs, 64);
    }
    if (slot == 0) {
        float dv = dinv[node];
        float4 s0 = H4[(size_t)node * 8 + feat4];
        float4 s1 = H4[(size_t)node * 8 + 4 + feat4];
        float4 c0 = b4[feat4];
        float4 c1 = b4[feat4 + 4];
        float4 r0, r1;
        r0.x = fmaf(lo.x + s0.x, dv, c0.x);
        r0.y = fmaf(lo.y + s0.y, dv, c0.y);
        r0.z = fmaf(lo.z + s0.z, dv, c0.z);
        r0.w = fmaf(lo.w + s0.w, dv, c0.w);
        r1.x = fmaf(hi.x + s1.x, dv, c1.x);
        r1.y = fmaf(hi.y + s1.y, dv, c1.y);
        r1.z = fmaf(hi.z + s1.z, dv, c1.z);
        r1.w = fmaf(hi.w + s1.w, dv, c1.w);
        out4[(size_t)node * 8 + feat4] = r0;
        out4[(size_t)node * 8 + 4 + feat4] = r1;
    }
}

// ---- FC: Y[n,1024] = X[n,32] @ W[32,1024] + bias ------------------------
// 2 adjacent W cols/thread (64 weight VGPRs), 32 rows/block, 4 blocks/CU
// (16 waves/CU) so the fma chain overlaps the nt-store stream.
__global__ __launch_bounds__(TB, 4)
void k_fc2(const float* __restrict__ X, const float* __restrict__ W,
           const float* __restrict__ bias, float* __restrict__ Y, int n) {
    __shared__ float Xs[FC_ROWS * 32];
    int c0 = blockIdx.x * 512 + threadIdx.x * 2;  // grid.x = 2 covers 1024 cols
    int r0 = blockIdx.y * FC_ROWS;
    int rows = min(FC_ROWS, n - r0);

    f32x2 w[32];
#pragma unroll
    for (int k = 0; k < 32; ++k) w[k] = *(const f32x2*)(W + k * 1024 + c0);
    f32x2 bb = *(const f32x2*)(bias + c0);

    {
        const float4* Xg = (const float4*)(X + (size_t)r0 * 32);
        float4* Xs4 = (float4*)Xs;
        int tot4 = rows * 8;
        for (int i = threadIdx.x; i < tot4; i += TB) Xs4[i] = Xg[i];
    }
    __syncthreads();

    for (int r = 0; r < rows; ++r) {
        const float* x = Xs + r * 32;
        float a0 = bb.x, a1 = bb.y;
#pragma unroll
        for (int k = 0; k < 32; ++k) {
            float xv = x[k];
            a0 = fmaf(xv, w[k].x, a0);
            a1 = fmaf(xv, w[k].y, a1);
        }
        f32x2 v;
        v.x = a0; v.y = a1;
        __builtin_nontemporal_store(v, (f32x2*)(Y + (size_t)(r0 + r) * 1024 + c0));
    }
}

// ---- launch -------------------------------------------------------------

extern "C" void kernel_launch(void* const* d_in, const int* in_sizes, int n_in,
                              void* d_out, int out_size, void* d_ws, size_t ws_size,
                              hipStream_t stream) {
    const float* z   = (const float*)d_in[0];
    const int*   ei  = (const int*)d_in[1];
    const float* W1  = (const float*)d_in[2];
    const float* b1  = (const float*)d_in[3];
    const float* W2  = (const float*)d_in[4];
    const float* b2  = (const float*)d_in[5];
    const float* Wfc = (const float*)d_in[6];
    const float* bfc = (const float*)d_in[7];
    float* out = (float*)d_out;

    int n = in_sizes[0] / 64;
    int E = in_sizes[1] / 2;
    const int* src = ei;
    const int* dst = ei + E;

    // Workspace layout (4-byte words):
    //   cnt[nPad] | work[16] | off[n+1] | slot[E] | eSrc[E] | dinv[n] | bufA[n*64] | bufB[n*64]
    int nPad = (n + 3) & ~3;
    int* cnt    = (int*)d_ws;
    int* work   = cnt + nPad;
    int* off    = work + 16;
    int* slot   = off + (n + 1);
    int* eSrc   = slot + E;
    float* dinv = (float*)(eSrc + E);
    float* bufA = dinv + n;
    float* bufB = bufA + (size_t)n * 64;
    float* h2   = bufA;
    float* agg2 = bufA + (size_t)n * 32;

    int nChunks = (n + SCHUNK - 1) / SCHUNK;

    // ---- CSR build + norms ----
    {
        int n4 = (nPad + 16) / 4;  // zero cnt + work together
        k_zero<<<(n4 + TB - 1) / TB, TB, 0, stream>>>((int4*)cnt, n4);
    }
    k_hist<<<(E + TB - 1) / TB, TB, 0, stream>>>(dst, cnt, slot, E);
    k_scanLB<<<nChunks, 1024, 0, stream>>>(cnt, off, dinv, work, n, E);

    // ---- union: CSR fill + conv1 GEMM (both depend only on scanLB) ----
    {
        int fillBlocks = (E + TB - 1) / TB;
        int gemmBlocks = (n + 15) / 16;
        k_fill_gemm<<<fillBlocks + gemmBlocks, TB, 0, stream>>>(
            src, dst, off, slot, eSrc, E, fillBlocks, z, W1, dinv, bufA, n);
    }

    // ---- conv1 agg: gather (+b1, relu) -> bufB ----
    k_agg64<<<(n + 3) / 4, TB, 0, stream>>>((const float4*)bufA, off, eSrc, dinv,
                                            (const float4*)b1, (float4*)bufB, n);

    // ---- conv2: h2' = dinv .* (bufB @ W2) ; gather-agg (+b2) -> agg2 ----
    k_gemm_64_32<<<(n + 31) / 32, TB, 0, stream>>>(bufB, W2, dinv, h2, n);
    k_agg32<<<(n + 3) / 4, TB, 0, stream>>>((const float4*)h2, off, eSrc, dinv,
                                            (const float4*)b2, (float4*)agg2, n);

    // ---- fc: out = agg2 @ Wfc + bfc ----
    {
        dim3 grid(2, (n + FC_ROWS - 1) / FC_ROWS);
        k_fc2<<<grid, TB, 0, stream>>>(agg2, Wfc, bfc, out, n);
    }
}

// Round 12
// 210.901 us; speedup vs baseline: 1.1861x; 1.0346x over previous
//
#include <hip/hip_runtime.h>

// GCN decoder: 2x GCNConv (self-loops, symmetric norm) + FC to 1024.
// n = 50000 nodes, E = 800000 directed edges, feats 64 -> 64 -> 32 -> 1024.
// Round 12: shuffle-free agg kernels (lane = feature group, per-lane serial
//           edge walk with 4-way unroll / 4 accumulators). Removes ~24-32
//           cross-lane DS ops per node. Rest frozen from round 11.

#define TB 256
#define FC_ROWS 32
#define SCHUNK 4096        // scan elements per block (1024 thr x 4)
#define FLAGB (1 << 30)    // scan "total published" flag bit (totals < 2^20)

typedef __attribute__((ext_vector_type(2))) float f32x2;

// ---- utility ------------------------------------------------------------

__global__ void k_zero(int4* __restrict__ p, int n4) {
    int i = blockIdx.x * TB + threadIdx.x;
    if (i < n4) p[i] = make_int4(0, 0, 0, 0);
}

// ---- CSR build ----------------------------------------------------------

// Count in-degree; record each edge's slot within its dst list.
__global__ void k_hist(const int* __restrict__ dst, int* __restrict__ cnt,
                       int* __restrict__ slot, int E) {
    int e = blockIdx.x * TB + threadIdx.x;
    if (e < E) slot[e] = atomicAdd(&cnt[dst[e]], 1);
}

// Exclusive scan of cnt -> off (+ fused dinv), one kernel via decoupled
// lookback. nChunks (<=13) blocks are trivially co-resident, so the spin on
// predecessors' published totals cannot deadlock regardless of dispatch order.
__global__ __launch_bounds__(1024)
void k_scanLB(const int* __restrict__ cnt, int* __restrict__ off,
              float* __restrict__ dinv, int* __restrict__ work, int n, int E) {
    __shared__ int wsum[16];
    __shared__ int pfx_s;
    int b = blockIdx.x;
    int i4 = b * SCHUNK + threadIdx.x * 4;
    int lane = threadIdx.x & 63, wid = threadIdx.x >> 6;
    int v0 = 0, v1 = 0, v2 = 0, v3 = 0;
    if (i4 + 3 < n) {
        int4 t = *(const int4*)(cnt + i4);
        v0 = t.x; v1 = t.y; v2 = t.z; v3 = t.w;
    } else {
        if (i4 < n) v0 = cnt[i4];
        if (i4 + 1 < n) v1 = cnt[i4 + 1];
        if (i4 + 2 < n) v2 = cnt[i4 + 2];
        if (i4 + 3 < n) v3 = cnt[i4 + 3];
    }
    // dinv needs no prefix -- store immediately (overlaps the lookback)
    if (i4 < n)     dinv[i4]     = rsqrtf((float)(v0 + 1));
    if (i4 + 1 < n) dinv[i4 + 1] = rsqrtf((float)(v1 + 1));
    if (i4 + 2 < n) dinv[i4 + 2] = rsqrtf((float)(v2 + 1));
    if (i4 + 3 < n) dinv[i4 + 3] = rsqrtf((float)(v3 + 1));

    int s = v0 + v1 + v2 + v3;
    int x = s;
#pragma unroll
    for (int ofs = 1; ofs < 64; ofs <<= 1) {
        int t = __shfl_up(x, ofs, 64);
        if (lane >= ofs) x += t;
    }
    if (lane == 63) wsum[wid] = x;
    __syncthreads();
    int wp = 0;
#pragma unroll
    for (int wv = 0; wv < 16; ++wv) wp += (wv < wid) ? wsum[wv] : 0;
    int excl = wp + x - s;

    if (threadIdx.x == 0) {
        int tot = 0;
#pragma unroll
        for (int wv = 0; wv < 16; ++wv) tot += wsum[wv];
        atomicOr(&work[b], tot | FLAGB);         // publish own total first
        int pfx = 0;
        for (int j = 0; j < b; ++j) {            // then wait on predecessors
            int v;
            do { v = atomicOr(&work[j], 0); } while (!(v & FLAGB));
            pfx += v & (FLAGB - 1);
        }
        pfx_s = pfx;
        if (b == 0) off[n] = E;
    }
    __syncthreads();
    excl += pfx_s;
    if (i4 < n)     off[i4]     = excl;
    if (i4 + 1 < n) off[i4 + 1] = excl + v0;
    if (i4 + 2 < n) off[i4 + 2] = excl + v0 + v1;
    if (i4 + 3 < n) off[i4 + 3] = excl + v0 + v1 + v2;
}

// ---- union dispatch: CSR fill (blocks [0,fillBlocks)) + conv1 GEMM -------
__global__ void k_fill_gemm(const int* __restrict__ src, const int* __restrict__ dst,
                            const int* __restrict__ off, const int* __restrict__ slot,
                            int* __restrict__ eSrc, int E, int fillBlocks,
                            const float* __restrict__ X, const float* __restrict__ W,
                            const float* __restrict__ dinv, float* __restrict__ Y, int n) {
    __shared__ float Ws[64 * 64];
    __shared__ float Xs[16 * 64];
    if ((int)blockIdx.x < fillBlocks) {
        int e = blockIdx.x * TB + threadIdx.x;
        if (e < E) eSrc[off[dst[e]] + slot[e]] = src[e];
        return;
    }
    int gb = blockIdx.x - fillBlocks;
    for (int i = threadIdx.x; i < 64 * 64; i += TB) Ws[i] = W[i];
    int r0 = gb * 16;
    int rows = min(16, n - r0);
    {
        const float4* Xg = (const float4*)(X + (size_t)r0 * 64);
        float4* Xs4 = (float4*)Xs;
        int tot4 = rows * 16;
        for (int i = threadIdx.x; i < tot4; i += TB) Xs4[i] = Xg[i];
    }
    __syncthreads();
    int c = threadIdx.x & 63;
    int g = threadIdx.x >> 6;  // 0..3
#pragma unroll
    for (int rr = 0; rr < 4; ++rr) {
        int rb = g + rr * 4;
        int r = r0 + rb;
        if (r >= n) break;
        const float* x = Xs + rb * 64;
        float acc = 0.f;
#pragma unroll
        for (int k = 0; k < 64; ++k) acc = fmaf(x[k], Ws[k * 64 + c], acc);
        Y[(size_t)r * 64 + c] = acc * dinv[r];
    }
}

// ---- conv2 GEMM (epilogue scales row by dinv[r]) -------------------------

__global__ void k_gemm_64_32(const float* __restrict__ X, const float* __restrict__ W,
                             const float* __restrict__ dinv, float* __restrict__ Y, int n) {
    __shared__ float Ws[64 * 32];
    __shared__ float Xs[32 * 64];
    for (int i = threadIdx.x; i < 64 * 32; i += TB) Ws[i] = W[i];
    int r0 = blockIdx.x * 32;
    int rows = min(32, n - r0);
    {
        const float4* Xg = (const float4*)(X + (size_t)r0 * 64);
        float4* Xs4 = (float4*)Xs;
        int tot4 = rows * 16;
        for (int i = threadIdx.x; i < tot4; i += TB) Xs4[i] = Xg[i];
    }
    __syncthreads();
    int c = threadIdx.x & 31;
    int g = threadIdx.x >> 5;  // 0..7
#pragma unroll
    for (int rr = 0; rr < 4; ++rr) {
        int rb = g + rr * 8;
        int r = r0 + rb;
        if (r >= n) break;
        const float* x = Xs + rb * 64;
        float acc = 0.f;
#pragma unroll
        for (int k = 0; k < 64; ++k) acc = fmaf(x[k], Ws[k * 32 + c], acc);
        Y[(size_t)r * 32 + c] = acc * dinv[r];
    }
}

// ---- gather aggregation on pre-scaled H' (= dinv .* H), shuffle-free -----
// out[i] = relu?( (sum_{s in N(i)} H'[s] + H'[i]) * dinv[i] + b )
// agg64: 16 lanes per node (lane = feat4 0..15); each lane walks the node's
// full edge list, 4-way unrolled (4 independent gathers in flight). No
// cross-lane ops, no idle epilogue lanes.

__global__ void k_agg64(const float4* __restrict__ H4, const int* __restrict__ off,
                        const int* __restrict__ eSrc, const float* __restrict__ dinv,
                        const float4* __restrict__ b4, float4* __restrict__ out4, int n) {
    int node = blockIdx.x * 16 + (threadIdx.x >> 4);
    if (node >= n) return;
    int feat4 = threadIdx.x & 15;
    int j0 = off[node], j1 = off[node + 1];
    float4 a0 = make_float4(0.f, 0.f, 0.f, 0.f);
    float4 a1 = make_float4(0.f, 0.f, 0.f, 0.f);
    float4 a2 = make_float4(0.f, 0.f, 0.f, 0.f);
    float4 a3 = make_float4(0.f, 0.f, 0.f, 0.f);
    int e = j0;
    for (; e + 4 <= j1; e += 4) {
        int s0 = eSrc[e], s1 = eSrc[e + 1], s2 = eSrc[e + 2], s3 = eSrc[e + 3];
        float4 v0 = H4[(size_t)s0 * 16 + feat4];
        float4 v1 = H4[(size_t)s1 * 16 + feat4];
        float4 v2 = H4[(size_t)s2 * 16 + feat4];
        float4 v3 = H4[(size_t)s3 * 16 + feat4];
        a0.x += v0.x; a0.y += v0.y; a0.z += v0.z; a0.w += v0.w;
        a1.x += v1.x; a1.y += v1.y; a1.z += v1.z; a1.w += v1.w;
        a2.x += v2.x; a2.y += v2.y; a2.z += v2.z; a2.w += v2.w;
        a3.x += v3.x; a3.y += v3.y; a3.z += v3.z; a3.w += v3.w;
    }
    for (; e < j1; ++e) {
        float4 v = H4[(size_t)eSrc[e] * 16 + feat4];
        a0.x += v.x; a0.y += v.y; a0.z += v.z; a0.w += v.w;
    }
    float4 self = H4[(size_t)node * 16 + feat4];
    float dv = dinv[node];
    float4 bb = b4[feat4];
    float4 r;
    r.x = fmaxf(fmaf((a0.x + a1.x) + (a2.x + a3.x) + self.x, dv, bb.x), 0.f);
    r.y = fmaxf(fmaf((a0.y + a1.y) + (a2.y + a3.y) + self.y, dv, bb.y), 0.f);
    r.z = fmaxf(fmaf((a0.z + a1.z) + (a2.z + a3.z) + self.z, dv, bb.z), 0.f);
    r.w = fmaxf(fmaf((a0.w + a1.w) + (a2.w + a3.w) + self.w, dv, bb.w), 0.f);
    out4[(size_t)node * 16 + feat4] = r;
}

// agg32: 8 lanes per node (lane = feat4 0..7); same structure, no relu.
__global__ void k_agg32(const float4* __restrict__ H4, const int* __restrict__ off,
                        const int* __restrict__ eSrc, const float* __restrict__ dinv,
                        const float4* __restrict__ b4, float4* __restrict__ out4, int n) {
    int node = blockIdx.x * 32 + (threadIdx.x >> 3);
    if (node >= n) return;
    int feat4 = threadIdx.x & 7;
    int j0 = off[node], j1 = off[node + 1];
    float4 a0 = make_float4(0.f, 0.f, 0.f, 0.f);
    float4 a1 = make_float4(0.f, 0.f, 0.f, 0.f);
    float4 a2 = make_float4(0.f, 0.f, 0.f, 0.f);
    float4 a3 = make_float4(0.f, 0.f, 0.f, 0.f);
    int e = j0;
    for (; e + 4 <= j1; e += 4) {
        int s0 = eSrc[e], s1 = eSrc[e + 1], s2 = eSrc[e + 2], s3 = eSrc[e + 3];
        float4 v0 = H4[(size_t)s0 * 8 + feat4];
        float4 v1 = H4[(size_t)s1 * 8 + feat4];
        float4 v2 = H4[(size_t)s2 * 8 + feat4];
        float4 v3 = H4[(size_t)s3 * 8 + feat4];
        a0.x += v0.x; a0.y += v0.y; a0.z += v0.z; a0.w += v0.w;
        a1.x += v1.x; a1.y += v1.y; a1.z += v1.z; a1.w += v1.w;
        a2.x += v2.x; a2.y += v2.y; a2.z += v2.z; a2.w += v2.w;
        a3.x += v3.x; a3.y += v3.y; a3.z += v3.z; a3.w += v3.w;
    }
    for (; e < j1; ++e) {
        float4 v = H4[(size_t)eSrc[e] * 8 + feat4];
        a0.x += v.x; a0.y += v.y; a0.z += v.z; a0.w += v.w;
    }
    float4 self = H4[(size_t)node * 8 + feat4];
    float dv = dinv[node];
    float4 bb = b4[feat4];
    float4 r;
    r.x = fmaf((a0.x + a1.x) + (a2.x + a3.x) + self.x, dv, bb.x);
    r.y = fmaf((a0.y + a1.y) + (a2.y + a3.y) + self.y, dv, bb.y);
    r.z = fmaf((a0.z + a1.z) + (a2.z + a3.z) + self.z, dv, bb.z);
    r.w = fmaf((a0.w + a1.w) + (a2.w + a3.w) + self.w, dv, bb.w);
    out4[(size_t)node * 8 + feat4] = r;
}

// ---- FC: Y[n,1024] = X[n,32] @ W[32,1024] + bias ------------------------
// 2 adjacent W cols/thread (64 weight VGPRs), 32 rows/block, 4 blocks/CU
// (16 waves/CU) so the fma chain overlaps the nt-store stream.
__global__ __launch_bounds__(TB, 4)
void k_fc2(const float* __restrict__ X, const float* __restrict__ W,
           const float* __restrict__ bias, float* __restrict__ Y, int n) {
    __shared__ float Xs[FC_ROWS * 32];
    int c0 = blockIdx.x * 512 + threadIdx.x * 2;  // grid.x = 2 covers 1024 cols
    int r0 = blockIdx.y * FC_ROWS;
    int rows = min(FC_ROWS, n - r0);

    f32x2 w[32];
#pragma unroll
    for (int k = 0; k < 32; ++k) w[k] = *(const f32x2*)(W + k * 1024 + c0);
    f32x2 bb = *(const f32x2*)(bias + c0);

    {
        const float4* Xg = (const float4*)(X + (size_t)r0 * 32);
        float4* Xs4 = (float4*)Xs;
        int tot4 = rows * 8;
        for (int i = threadIdx.x; i < tot4; i += TB) Xs4[i] = Xg[i];
    }
    __syncthreads();

    for (int r = 0; r < rows; ++r) {
        const float* x = Xs + r * 32;
        float a0 = bb.x, a1 = bb.y;
#pragma unroll
        for (int k = 0; k < 32; ++k) {
            float xv = x[k];
            a0 = fmaf(xv, w[k].x, a0);
            a1 = fmaf(xv, w[k].y, a1);
        }
        f32x2 v;
        v.x = a0; v.y = a1;
        __builtin_nontemporal_store(v, (f32x2*)(Y + (size_t)(r0 + r) * 1024 + c0));
    }
}

// ---- launch -------------------------------------------------------------

extern "C" void kernel_launch(void* const* d_in, const int* in_sizes, int n_in,
                              void* d_out, int out_size, void* d_ws, size_t ws_size,
                              hipStream_t stream) {
    const float* z   = (const float*)d_in[0];
    const int*   ei  = (const int*)d_in[1];
    const float* W1  = (const float*)d_in[2];
    const float* b1  = (const float*)d_in[3];
    const float* W2  = (const float*)d_in[4];
    const float* b2  = (const float*)d_in[5];
    const float* Wfc = (const float*)d_in[6];
    const float* bfc = (const float*)d_in[7];
    float* out = (float*)d_out;

    int n = in_sizes[0] / 64;
    int E = in_sizes[1] / 2;
    const int* src = ei;
    const int* dst = ei + E;

    // Workspace layout (4-byte words):
    //   cnt[nPad] | work[16] | off[n+1] | slot[E] | eSrc[E] | dinv[n] | bufA[n*64] | bufB[n*64]
    int nPad = (n + 3) & ~3;
    int* cnt    = (int*)d_ws;
    int* work   = cnt + nPad;
    int* off    = work + 16;
    int* slot   = off + (n + 1);
    int* eSrc   = slot + E;
    float* dinv = (float*)(eSrc + E);
    float* bufA = dinv + n;
    float* bufB = bufA + (size_t)n * 64;
    float* h2   = bufA;
    float* agg2 = bufA + (size_t)n * 32;

    int nChunks = (n + SCHUNK - 1) / SCHUNK;

    // ---- CSR build + norms ----
    {
        int n4 = (nPad + 16) / 4;  // zero cnt + work together
        k_zero<<<(n4 + TB - 1) / TB, TB, 0, stream>>>((int4*)cnt, n4);
    }
    k_hist<<<(E + TB - 1) / TB, TB, 0, stream>>>(dst, cnt, slot, E);
    k_scanLB<<<nChunks, 1024, 0, stream>>>(cnt, off, dinv, work, n, E);

    // ---- union: CSR fill + conv1 GEMM (both depend only on scanLB) ----
    {
        int fillBlocks = (E + TB - 1) / TB;
        int gemmBlocks = (n + 15) / 16;
        k_fill_gemm<<<fillBlocks + gemmBlocks, TB, 0, stream>>>(
            src, dst, off, slot, eSrc, E, fillBlocks, z, W1, dinv, bufA, n);
    }

    // ---- conv1 agg: gather (+b1, relu) -> bufB ----
    k_agg64<<<(n + 15) / 16, TB, 0, stream>>>((const float4*)bufA, off, eSrc, dinv,
                                              (const float4*)b1, (float4*)bufB, n);

    // ---- conv2: h2' = dinv .* (bufB @ W2) ; gather-agg (+b2) -> agg2 ----
    k_gemm_64_32<<<(n + 31) / 32, TB, 0, stream>>>(bufB, W2, dinv, h2, n);
    k_agg32<<<(n + 31) / 32, TB, 0, stream>>>((const float4*)h2, off, eSrc, dinv,
                                              (const float4*)b2, (float4*)agg2, n);

    // ---- fc: out = agg2 @ Wfc + bfc ----
    {
        dim3 grid(2, (n + FC_ROWS - 1) / FC_ROWS);
        k_fc2<<<grid, TB, 0, stream>>>(agg2, Wfc, bfc, out, n);
    }
}

// Round 13
// 186.703 us; speedup vs baseline: 1.3398x; 1.1296x over previous
//
#include <hip/hip_runtime.h>

// GCN decoder: 2x GCNConv (self-loops, symmetric norm) + FC to 1024.
// n = 50000 nodes, E = 800000 directed edges, feats 64 -> 64 -> 32 -> 1024.
// Round 13: bf16 staging for the GATHERED activations (h1', h2') -- halves
//           agg gather traffic (218->109MB, 109->55MB) and halves the
//           L2 footprint (12.8->6.4MB vs 4MB/XCD L2). f32 everywhere else.

#define TB 256
#define FC_ROWS 32
#define SCHUNK 4096        // scan elements per block (1024 thr x 4)
#define FLAGB (1 << 30)    // scan "total published" flag bit (totals < 2^20)

typedef __attribute__((ext_vector_type(2))) float f32x2;

// f32 -> bf16 with round-to-nearest-even (exact, branchless)
__device__ __forceinline__ unsigned short f2bf(float f) {
    unsigned u = __float_as_uint(f);
    u += 0x7fffu + ((u >> 16) & 1u);
    return (unsigned short)(u >> 16);
}

// accumulate 4 bf16 (packed in uint2) into a float4 (bf16->f32 widening is exact)
__device__ __forceinline__ void bf4_accum(uint2 p, float4& a) {
    a.x += __uint_as_float(p.x << 16);
    a.y += __uint_as_float(p.x & 0xffff0000u);
    a.z += __uint_as_float(p.y << 16);
    a.w += __uint_as_float(p.y & 0xffff0000u);
}

// ---- utility ------------------------------------------------------------

__global__ void k_zero(int4* __restrict__ p, int n4) {
    int i = blockIdx.x * TB + threadIdx.x;
    if (i < n4) p[i] = make_int4(0, 0, 0, 0);
}

// ---- CSR build ----------------------------------------------------------

__global__ void k_hist(const int* __restrict__ dst, int* __restrict__ cnt,
                       int* __restrict__ slot, int E) {
    int e = blockIdx.x * TB + threadIdx.x;
    if (e < E) slot[e] = atomicAdd(&cnt[dst[e]], 1);
}

// Exclusive scan of cnt -> off (+ fused dinv), decoupled lookback (<=13 blocks,
// all co-resident so the spin cannot deadlock).
__global__ __launch_bounds__(1024)
void k_scanLB(const int* __restrict__ cnt, int* __restrict__ off,
              float* __restrict__ dinv, int* __restrict__ work, int n, int E) {
    __shared__ int wsum[16];
    __shared__ int pfx_s;
    int b = blockIdx.x;
    int i4 = b * SCHUNK + threadIdx.x * 4;
    int lane = threadIdx.x & 63, wid = threadIdx.x >> 6;
    int v0 = 0, v1 = 0, v2 = 0, v3 = 0;
    if (i4 + 3 < n) {
        int4 t = *(const int4*)(cnt + i4);
        v0 = t.x; v1 = t.y; v2 = t.z; v3 = t.w;
    } else {
        if (i4 < n) v0 = cnt[i4];
        if (i4 + 1 < n) v1 = cnt[i4 + 1];
        if (i4 + 2 < n) v2 = cnt[i4 + 2];
        if (i4 + 3 < n) v3 = cnt[i4 + 3];
    }
    if (i4 < n)     dinv[i4]     = rsqrtf((float)(v0 + 1));
    if (i4 + 1 < n) dinv[i4 + 1] = rsqrtf((float)(v1 + 1));
    if (i4 + 2 < n) dinv[i4 + 2] = rsqrtf((float)(v2 + 1));
    if (i4 + 3 < n) dinv[i4 + 3] = rsqrtf((float)(v3 + 1));

    int s = v0 + v1 + v2 + v3;
    int x = s;
#pragma unroll
    for (int ofs = 1; ofs < 64; ofs <<= 1) {
        int t = __shfl_up(x, ofs, 64);
        if (lane >= ofs) x += t;
    }
    if (lane == 63) wsum[wid] = x;
    __syncthreads();
    int wp = 0;
#pragma unroll
    for (int wv = 0; wv < 16; ++wv) wp += (wv < wid) ? wsum[wv] : 0;
    int excl = wp + x - s;

    if (threadIdx.x == 0) {
        int tot = 0;
#pragma unroll
        for (int wv = 0; wv < 16; ++wv) tot += wsum[wv];
        atomicOr(&work[b], tot | FLAGB);
        int pfx = 0;
        for (int j = 0; j < b; ++j) {
            int v;
            do { v = atomicOr(&work[j], 0); } while (!(v & FLAGB));
            pfx += v & (FLAGB - 1);
        }
        pfx_s = pfx;
        if (b == 0) off[n] = E;
    }
    __syncthreads();
    excl += pfx_s;
    if (i4 < n)     off[i4]     = excl;
    if (i4 + 1 < n) off[i4 + 1] = excl + v0;
    if (i4 + 2 < n) off[i4 + 2] = excl + v0 + v1;
    if (i4 + 3 < n) off[i4 + 3] = excl + v0 + v1 + v2;
}

// ---- union dispatch: CSR fill + conv1 GEMM (both depend only on scanLB) --
// gemm: Y(bf16)[r,c] = bf16( dinv[r] * sum_k X[r,k] W[k,c] )
__global__ void k_fill_gemm(const int* __restrict__ src, const int* __restrict__ dst,
                            const int* __restrict__ off, const int* __restrict__ slot,
                            int* __restrict__ eSrc, int E, int fillBlocks,
                            const float* __restrict__ X, const float* __restrict__ W,
                            const float* __restrict__ dinv,
                            unsigned short* __restrict__ Y, int n) {
    __shared__ float Ws[64 * 64];
    __shared__ float Xs[16 * 64];
    if ((int)blockIdx.x < fillBlocks) {
        int e = blockIdx.x * TB + threadIdx.x;
        if (e < E) eSrc[off[dst[e]] + slot[e]] = src[e];
        return;
    }
    int gb = blockIdx.x - fillBlocks;
    for (int i = threadIdx.x; i < 64 * 64; i += TB) Ws[i] = W[i];
    int r0 = gb * 16;
    int rows = min(16, n - r0);
    {
        const float4* Xg = (const float4*)(X + (size_t)r0 * 64);
        float4* Xs4 = (float4*)Xs;
        int tot4 = rows * 16;
        for (int i = threadIdx.x; i < tot4; i += TB) Xs4[i] = Xg[i];
    }
    __syncthreads();
    int c = threadIdx.x & 63;
    int g = threadIdx.x >> 6;  // 0..3
#pragma unroll
    for (int rr = 0; rr < 4; ++rr) {
        int rb = g + rr * 4;
        int r = r0 + rb;
        if (r >= n) break;
        const float* x = Xs + rb * 64;
        float acc = 0.f;
#pragma unroll
        for (int k = 0; k < 64; ++k) acc = fmaf(x[k], Ws[k * 64 + c], acc);
        Y[(size_t)r * 64 + c] = f2bf(acc * dinv[r]);
    }
}

// ---- conv2 GEMM: bf16 output ---------------------------------------------

__global__ void k_gemm_64_32(const float* __restrict__ X, const float* __restrict__ W,
                             const float* __restrict__ dinv,
                             unsigned short* __restrict__ Y, int n) {
    __shared__ float Ws[64 * 32];
    __shared__ float Xs[32 * 64];
    for (int i = threadIdx.x; i < 64 * 32; i += TB) Ws[i] = W[i];
    int r0 = blockIdx.x * 32;
    int rows = min(32, n - r0);
    {
        const float4* Xg = (const float4*)(X + (size_t)r0 * 64);
        float4* Xs4 = (float4*)Xs;
        int tot4 = rows * 16;
        for (int i = threadIdx.x; i < tot4; i += TB) Xs4[i] = Xg[i];
    }
    __syncthreads();
    int c = threadIdx.x & 31;
    int g = threadIdx.x >> 5;  // 0..7
#pragma unroll
    for (int rr = 0; rr < 4; ++rr) {
        int rb = g + rr * 8;
        int r = r0 + rb;
        if (r >= n) break;
        const float* x = Xs + rb * 64;
        float acc = 0.f;
#pragma unroll
        for (int k = 0; k < 64; ++k) acc = fmaf(x[k], Ws[k * 32 + c], acc);
        Y[(size_t)r * 32 + c] = f2bf(acc * dinv[r]);
    }
}

// ---- gather aggregation on bf16 H' (= dinv .* H), shuffle-free -----------
// agg64: 16 lanes/node (lane = 4-feat group); per-lane serial edge walk,
// 4-way unrolled; each gather is uint2 = 4 bf16 = 8B/lane. f32 accumulate.

__global__ void k_agg64(const uint2* __restrict__ H2, const int* __restrict__ off,
                        const int* __restrict__ eSrc, const float* __restrict__ dinv,
                        const float4* __restrict__ b4, float4* __restrict__ out4, int n) {
    int node = blockIdx.x * 16 + (threadIdx.x >> 4);
    if (node >= n) return;
    int feat4 = threadIdx.x & 15;
    int j0 = off[node], j1 = off[node + 1];
    float4 a0 = make_float4(0.f, 0.f, 0.f, 0.f);
    float4 a1 = make_float4(0.f, 0.f, 0.f, 0.f);
    float4 a2 = make_float4(0.f, 0.f, 0.f, 0.f);
    float4 a3 = make_float4(0.f, 0.f, 0.f, 0.f);
    int e = j0;
    for (; e + 4 <= j1; e += 4) {
        int s0 = eSrc[e], s1 = eSrc[e + 1], s2 = eSrc[e + 2], s3 = eSrc[e + 3];
        uint2 v0 = H2[(size_t)s0 * 16 + feat4];
        uint2 v1 = H2[(size_t)s1 * 16 + feat4];
        uint2 v2 = H2[(size_t)s2 * 16 + feat4];
        uint2 v3 = H2[(size_t)s3 * 16 + feat4];
        bf4_accum(v0, a0);
        bf4_accum(v1, a1);
        bf4_accum(v2, a2);
        bf4_accum(v3, a3);
    }
    for (; e < j1; ++e) bf4_accum(H2[(size_t)eSrc[e] * 16 + feat4], a0);
    float4 self = make_float4(0.f, 0.f, 0.f, 0.f);
    bf4_accum(H2[(size_t)node * 16 + feat4], self);
    float dv = dinv[node];
    float4 bb = b4[feat4];
    float4 r;
    r.x = fmaxf(fmaf((a0.x + a1.x) + (a2.x + a3.x) + self.x, dv, bb.x), 0.f);
    r.y = fmaxf(fmaf((a0.y + a1.y) + (a2.y + a3.y) + self.y, dv, bb.y), 0.f);
    r.z = fmaxf(fmaf((a0.z + a1.z) + (a2.z + a3.z) + self.z, dv, bb.z), 0.f);
    r.w = fmaxf(fmaf((a0.w + a1.w) + (a2.w + a3.w) + self.w, dv, bb.w), 0.f);
    out4[(size_t)node * 16 + feat4] = r;
}

// agg32: 8 lanes/node; same structure, no relu; f32 output (FC input).
__global__ void k_agg32(const uint2* __restrict__ H2, const int* __restrict__ off,
                        const int* __restrict__ eSrc, const float* __restrict__ dinv,
                        const float4* __restrict__ b4, float4* __restrict__ out4, int n) {
    int node = blockIdx.x * 32 + (threadIdx.x >> 3);
    if (node >= n) return;
    int feat4 = threadIdx.x & 7;
    int j0 = off[node], j1 = off[node + 1];
    float4 a0 = make_float4(0.f, 0.f, 0.f, 0.f);
    float4 a1 = make_float4(0.f, 0.f, 0.f, 0.f);
    float4 a2 = make_float4(0.f, 0.f, 0.f, 0.f);
    float4 a3 = make_float4(0.f, 0.f, 0.f, 0.f);
    int e = j0;
    for (; e + 4 <= j1; e += 4) {
        int s0 = eSrc[e], s1 = eSrc[e + 1], s2 = eSrc[e + 2], s3 = eSrc[e + 3];
        uint2 v0 = H2[(size_t)s0 * 8 + feat4];
        uint2 v1 = H2[(size_t)s1 * 8 + feat4];
        uint2 v2 = H2[(size_t)s2 * 8 + feat4];
        uint2 v3 = H2[(size_t)s3 * 8 + feat4];
        bf4_accum(v0, a0);
        bf4_accum(v1, a1);
        bf4_accum(v2, a2);
        bf4_accum(v3, a3);
    }
    for (; e < j1; ++e) bf4_accum(H2[(size_t)eSrc[e] * 8 + feat4], a0);
    float4 self = make_float4(0.f, 0.f, 0.f, 0.f);
    bf4_accum(H2[(size_t)node * 8 + feat4], self);
    float dv = dinv[node];
    float4 bb = b4[feat4];
    float4 r;
    r.x = fmaf((a0.x + a1.x) + (a2.x + a3.x) + self.x, dv, bb.x);
    r.y = fmaf((a0.y + a1.y) + (a2.y + a3.y) + self.y, dv, bb.y);
    r.z = fmaf((a0.z + a1.z) + (a2.z + a3.z) + self.z, dv, bb.z);
    r.w = fmaf((a0.w + a1.w) + (a2.w + a3.w) + self.w, dv, bb.w);
    out4[(size_t)node * 8 + feat4] = r;
}

// ---- FC: Y[n,1024] = X[n,32] @ W[32,1024] + bias ------------------------
// 2 adjacent W cols/thread (64 weight VGPRs), 32 rows/block, 4 blocks/CU.
__global__ __launch_bounds__(TB, 4)
void k_fc2(const float* __restrict__ X, const float* __restrict__ W,
           const float* __restrict__ bias, float* __restrict__ Y, int n) {
    __shared__ float Xs[FC_ROWS * 32];
    int c0 = blockIdx.x * 512 + threadIdx.x * 2;  // grid.x = 2 covers 1024 cols
    int r0 = blockIdx.y * FC_ROWS;
    int rows = min(FC_ROWS, n - r0);

    f32x2 w[32];
#pragma unroll
    for (int k = 0; k < 32; ++k) w[k] = *(const f32x2*)(W + k * 1024 + c0);
    f32x2 bb = *(const f32x2*)(bias + c0);

    {
        const float4* Xg = (const float4*)(X + (size_t)r0 * 32);
        float4* Xs4 = (float4*)Xs;
        int tot4 = rows * 8;
        for (int i = threadIdx.x; i < tot4; i += TB) Xs4[i] = Xg[i];
    }
    __syncthreads();

    for (int r = 0; r < rows; ++r) {
        const float* x = Xs + r * 32;
        float a0 = bb.x, a1 = bb.y;
#pragma unroll
        for (int k = 0; k < 32; ++k) {
            float xv = x[k];
            a0 = fmaf(xv, w[k].x, a0);
            a1 = fmaf(xv, w[k].y, a1);
        }
        f32x2 v;
        v.x = a0; v.y = a1;
        __builtin_nontemporal_store(v, (f32x2*)(Y + (size_t)(r0 + r) * 1024 + c0));
    }
}

// ---- launch -------------------------------------------------------------

extern "C" void kernel_launch(void* const* d_in, const int* in_sizes, int n_in,
                              void* d_out, int out_size, void* d_ws, size_t ws_size,
                              hipStream_t stream) {
    const float* z   = (const float*)d_in[0];
    const int*   ei  = (const int*)d_in[1];
    const float* W1  = (const float*)d_in[2];
    const float* b1  = (const float*)d_in[3];
    const float* W2  = (const float*)d_in[4];
    const float* b2  = (const float*)d_in[5];
    const float* Wfc = (const float*)d_in[6];
    const float* bfc = (const float*)d_in[7];
    float* out = (float*)d_out;

    int n = in_sizes[0] / 64;
    int E = in_sizes[1] / 2;
    const int* src = ei;
    const int* dst = ei + E;

    // Workspace layout (4-byte words, all sub-buffers 16B aligned):
    //   cnt[nPad] | work[16] | off[n+1 pad4] | slot[E] | eSrc[E] | dinv[n]
    //   | h1b (n*64 bf16 = n*32 words) | bufB (n*64 f32)
    //   | h2b (n*32 bf16 = n*16 words) | agg2 (n*32 f32)
    int nPad = (n + 3) & ~3;
    int* cnt    = (int*)d_ws;
    int* work   = cnt + nPad;
    int* off    = work + 16;
    int* slot   = off + ((n + 1 + 3) & ~3);
    int* eSrc   = slot + E;
    float* dinv = (float*)(eSrc + E);
    unsigned short* h1b = (unsigned short*)(dinv + n);        // n*64 bf16
    float* bufB = (float*)(dinv + n + (size_t)n * 32);        // n*64 f32
    unsigned short* h2b = (unsigned short*)(bufB + (size_t)n * 64);  // n*32 bf16
    float* agg2 = bufB + (size_t)n * 64 + (size_t)n * 16;     // n*32 f32

    int nChunks = (n + SCHUNK - 1) / SCHUNK;

    // ---- CSR build + norms ----
    {
        int n4 = (nPad + 16) / 4;  // zero cnt + work together
        k_zero<<<(n4 + TB - 1) / TB, TB, 0, stream>>>((int4*)cnt, n4);
    }
    k_hist<<<(E + TB - 1) / TB, TB, 0, stream>>>(dst, cnt, slot, E);
    k_scanLB<<<nChunks, 1024, 0, stream>>>(cnt, off, dinv, work, n, E);

    // ---- union: CSR fill + conv1 GEMM (bf16 out) ----
    {
        int fillBlocks = (E + TB - 1) / TB;
        int gemmBlocks = (n + 15) / 16;
        k_fill_gemm<<<fillBlocks + gemmBlocks, TB, 0, stream>>>(
            src, dst, off, slot, eSrc, E, fillBlocks, z, W1, dinv, h1b, n);
    }

    // ---- conv1 agg: bf16 gather (+b1, relu) -> bufB (f32) ----
    k_agg64<<<(n + 15) / 16, TB, 0, stream>>>((const uint2*)h1b, off, eSrc, dinv,
                                              (const float4*)b1, (float4*)bufB, n);

    // ---- conv2: h2b = bf16(dinv .* (bufB @ W2)) ; bf16 gather (+b2) -> agg2 ----
    k_gemm_64_32<<<(n + 31) / 32, TB, 0, stream>>>(bufB, W2, dinv, h2b, n);
    k_agg32<<<(n + 31) / 32, TB, 0, stream>>>((const uint2*)h2b, off, eSrc, dinv,
                                              (const float4*)b2, (float4*)agg2, n);

    // ---- fc: out = agg2 @ Wfc + bfc ----
    {
        dim3 grid(2, (n + FC_ROWS - 1) / FC_ROWS);
        k_fc2<<<grid, TB, 0, stream>>>(agg2, Wfc, bfc, out, n);
    }
}

// Round 14
// 183.546 us; speedup vs baseline: 1.3629x; 1.0172x over previous
//
#include <hip/hip_runtime.h>

// GCN decoder: 2x GCNConv (self-loops, symmetric norm) + FC to 1024.
// n = 50000 nodes, E = 800000 directed edges, feats 64 -> 64 -> 32 -> 1024.
// Round 14: block-local fusions preserving gather geometry:
//   agg64+gemm2  (conv1 rows stay in LDS; bufB 25.6MB round-trip removed)
//   agg32+FC     (64 nodes x 8 lanes phase A -> LDS -> register-blocked FC)
// 6 dispatches; bf16 staging as round 13.

#define TB 256
#define FCTB 512
#define SCHUNK 4096        // scan elements per block (1024 thr x 4)
#define FLAGB (1 << 30)    // scan "total published" flag bit

typedef __attribute__((ext_vector_type(2))) float f32x2;

// f32 -> bf16 round-to-nearest-even
__device__ __forceinline__ unsigned short f2bf(float f) {
    unsigned u = __float_as_uint(f);
    u += 0x7fffu + ((u >> 16) & 1u);
    return (unsigned short)(u >> 16);
}

// accumulate 4 bf16 (packed uint2) into float4 (widening exact)
__device__ __forceinline__ void bf4_accum(uint2 p, float4& a) {
    a.x += __uint_as_float(p.x << 16);
    a.y += __uint_as_float(p.x & 0xffff0000u);
    a.z += __uint_as_float(p.y << 16);
    a.w += __uint_as_float(p.y & 0xffff0000u);
}

// ---- utility ------------------------------------------------------------

__global__ void k_zero(int4* __restrict__ p, int n4) {
    int i = blockIdx.x * TB + threadIdx.x;
    if (i < n4) p[i] = make_int4(0, 0, 0, 0);
}

// ---- CSR build ----------------------------------------------------------

__global__ void k_hist(const int* __restrict__ dst, int* __restrict__ cnt,
                       int* __restrict__ slot, int E) {
    int e = blockIdx.x * TB + threadIdx.x;
    if (e < E) slot[e] = atomicAdd(&cnt[dst[e]], 1);
}

// Exclusive scan cnt -> off (+ fused dinv); decoupled lookback (<=13 blocks).
__global__ __launch_bounds__(1024)
void k_scanLB(const int* __restrict__ cnt, int* __restrict__ off,
              float* __restrict__ dinv, int* __restrict__ work, int n, int E) {
    __shared__ int wsum[16];
    __shared__ int pfx_s;
    int b = blockIdx.x;
    int i4 = b * SCHUNK + threadIdx.x * 4;
    int lane = threadIdx.x & 63, wid = threadIdx.x >> 6;
    int v0 = 0, v1 = 0, v2 = 0, v3 = 0;
    if (i4 + 3 < n) {
        int4 t = *(const int4*)(cnt + i4);
        v0 = t.x; v1 = t.y; v2 = t.z; v3 = t.w;
    } else {
        if (i4 < n) v0 = cnt[i4];
        if (i4 + 1 < n) v1 = cnt[i4 + 1];
        if (i4 + 2 < n) v2 = cnt[i4 + 2];
        if (i4 + 3 < n) v3 = cnt[i4 + 3];
    }
    if (i4 < n)     dinv[i4]     = rsqrtf((float)(v0 + 1));
    if (i4 + 1 < n) dinv[i4 + 1] = rsqrtf((float)(v1 + 1));
    if (i4 + 2 < n) dinv[i4 + 2] = rsqrtf((float)(v2 + 1));
    if (i4 + 3 < n) dinv[i4 + 3] = rsqrtf((float)(v3 + 1));

    int s = v0 + v1 + v2 + v3;
    int x = s;
#pragma unroll
    for (int ofs = 1; ofs < 64; ofs <<= 1) {
        int t = __shfl_up(x, ofs, 64);
        if (lane >= ofs) x += t;
    }
    if (lane == 63) wsum[wid] = x;
    __syncthreads();
    int wp = 0;
#pragma unroll
    for (int wv = 0; wv < 16; ++wv) wp += (wv < wid) ? wsum[wv] : 0;
    int excl = wp + x - s;

    if (threadIdx.x == 0) {
        int tot = 0;
#pragma unroll
        for (int wv = 0; wv < 16; ++wv) tot += wsum[wv];
        atomicOr(&work[b], tot | FLAGB);
        int pfx = 0;
        for (int j = 0; j < b; ++j) {
            int v;
            do { v = atomicOr(&work[j], 0); } while (!(v & FLAGB));
            pfx += v & (FLAGB - 1);
        }
        pfx_s = pfx;
        if (b == 0) off[n] = E;
    }
    __syncthreads();
    excl += pfx_s;
    if (i4 < n)     off[i4]     = excl;
    if (i4 + 1 < n) off[i4 + 1] = excl + v0;
    if (i4 + 2 < n) off[i4 + 2] = excl + v0 + v1;
    if (i4 + 3 < n) off[i4 + 3] = excl + v0 + v1 + v2;
}

// ---- union dispatch: CSR fill + conv1 GEMM (bf16 out) --------------------
__global__ void k_fill_gemm(const int* __restrict__ src, const int* __restrict__ dst,
                            const int* __restrict__ off, const int* __restrict__ slot,
                            int* __restrict__ eSrc, int E, int fillBlocks,
                            const float* __restrict__ X, const float* __restrict__ W,
                            const float* __restrict__ dinv,
                            unsigned short* __restrict__ Y, int n) {
    __shared__ float Ws[64 * 64];
    __shared__ float Xs[16 * 64];
    if ((int)blockIdx.x < fillBlocks) {
        int e = blockIdx.x * TB + threadIdx.x;
        if (e < E) eSrc[off[dst[e]] + slot[e]] = src[e];
        return;
    }
    int gb = blockIdx.x - fillBlocks;
    for (int i = threadIdx.x; i < 64 * 64; i += TB) Ws[i] = W[i];
    int r0 = gb * 16;
    int rows = min(16, n - r0);
    {
        const float4* Xg = (const float4*)(X + (size_t)r0 * 64);
        float4* Xs4 = (float4*)Xs;
        int tot4 = rows * 16;
        for (int i = threadIdx.x; i < tot4; i += TB) Xs4[i] = Xg[i];
    }
    __syncthreads();
    int c = threadIdx.x & 63;
    int g = threadIdx.x >> 6;  // 0..3
#pragma unroll
    for (int rr = 0; rr < 4; ++rr) {
        int rb = g + rr * 4;
        int r = r0 + rb;
        if (r >= n) break;
        const float* x = Xs + rb * 64;
        float acc = 0.f;
#pragma unroll
        for (int k = 0; k < 64; ++k) acc = fmaf(x[k], Ws[k * 64 + c], acc);
        Y[(size_t)r * 64 + c] = f2bf(acc * dinv[r]);
    }
}

// ---- fused conv1-agg + conv2-GEMM ----------------------------------------
// Phase A (agg64 geometry, unchanged): 16 nodes/block, 16 lanes/node,
// bf16 uint2 gathers, 4-way unroll -> post-relu rows into LDS.
// Phase B: h2b[nd,c] = bf16( dinv[nd] * rows[nd] @ W2[:,c] ), W2 in LDS.
__global__ void k_agg64g2(const uint2* __restrict__ H2, const int* __restrict__ off,
                          const int* __restrict__ eSrc, const float* __restrict__ dinv,
                          const float4* __restrict__ b4, const float* __restrict__ W2,
                          unsigned short* __restrict__ h2b, int n) {
    __shared__ float rowsS[16 * 64];  // 4KB
    __shared__ float W2s[64 * 32];    // 8KB
    for (int i = threadIdx.x; i < 64 * 32; i += TB) W2s[i] = W2[i];
    int r0 = blockIdx.x * 16;
    int node = r0 + (threadIdx.x >> 4);
    int feat4 = threadIdx.x & 15;
    if (node < n) {
        int j0 = off[node], j1 = off[node + 1];
        float4 a0 = make_float4(0.f, 0.f, 0.f, 0.f);
        float4 a1 = make_float4(0.f, 0.f, 0.f, 0.f);
        float4 a2 = make_float4(0.f, 0.f, 0.f, 0.f);
        float4 a3 = make_float4(0.f, 0.f, 0.f, 0.f);
        int e = j0;
        for (; e + 4 <= j1; e += 4) {
            int s0 = eSrc[e], s1 = eSrc[e + 1], s2 = eSrc[e + 2], s3 = eSrc[e + 3];
            bf4_accum(H2[(size_t)s0 * 16 + feat4], a0);
            bf4_accum(H2[(size_t)s1 * 16 + feat4], a1);
            bf4_accum(H2[(size_t)s2 * 16 + feat4], a2);
            bf4_accum(H2[(size_t)s3 * 16 + feat4], a3);
        }
        for (; e < j1; ++e) bf4_accum(H2[(size_t)eSrc[e] * 16 + feat4], a0);
        float4 self = make_float4(0.f, 0.f, 0.f, 0.f);
        bf4_accum(H2[(size_t)node * 16 + feat4], self);
        float dv = dinv[node];
        float4 bb = b4[feat4];
        float4 r;
        r.x = fmaxf(fmaf((a0.x + a1.x) + (a2.x + a3.x) + self.x, dv, bb.x), 0.f);
        r.y = fmaxf(fmaf((a0.y + a1.y) + (a2.y + a3.y) + self.y, dv, bb.y), 0.f);
        r.z = fmaxf(fmaf((a0.z + a1.z) + (a2.z + a3.z) + self.z, dv, bb.z), 0.f);
        r.w = fmaxf(fmaf((a0.w + a1.w) + (a2.w + a3.w) + self.w, dv, bb.w), 0.f);
        ((float4*)rowsS)[(threadIdx.x >> 4) * 16 + feat4] = r;
    }
    __syncthreads();
    // Phase B: 16 nodes x 32 cols = 512 outputs, 2 per thread.
#pragma unroll
    for (int rep = 0; rep < 2; ++rep) {
        int idx = rep * TB + threadIdx.x;
        int nd = idx >> 5, c = idx & 31;
        int gn = r0 + nd;
        if (gn < n) {
            const float* x = rowsS + nd * 64;
            float acc = 0.f;
#pragma unroll
            for (int k = 0; k < 64; ++k) acc = fmaf(x[k], W2s[k * 32 + c], acc);
            h2b[(size_t)gn * 32 + c] = f2bf(acc * dinv[gn]);
        }
    }
}

// ---- fused conv2-agg + FC ------------------------------------------------
// Phase A (agg32 geometry, unchanged per lane): 64 nodes/block, 8 lanes/node,
// bf16 uint2 gathers -> rows (f32, +b2, *dinv, no relu) into LDS.
// Phase B: register-blocked FC, 2 adjacent cols/thread (512 thr = 1024 cols),
// f32x2 nt stores. launch_bounds(512,4) -> 128 VGPR cap, 2 blocks/CU.
__global__ __launch_bounds__(FCTB, 4)
void k_aggfc(const uint2* __restrict__ H2, const int* __restrict__ off,
             const int* __restrict__ eSrc, const float* __restrict__ dinv,
             const float4* __restrict__ b4, const float* __restrict__ Wfc,
             const float* __restrict__ bfc, float* __restrict__ Y, int n) {
    __shared__ float Xs[64 * 32];  // 8KB
    int r0 = blockIdx.x * 64;
    int c0 = threadIdx.x * 2;

    f32x2 w[32];
#pragma unroll
    for (int k = 0; k < 32; ++k) w[k] = *(const f32x2*)(Wfc + k * 1024 + c0);
    f32x2 bb = *(const f32x2*)(bfc + c0);

    // ---- phase A ----
    int node = r0 + (threadIdx.x >> 3);
    int feat4 = threadIdx.x & 7;
    if (node < n) {
        int j0 = off[node], j1 = off[node + 1];
        float4 a0 = make_float4(0.f, 0.f, 0.f, 0.f);
        float4 a1 = make_float4(0.f, 0.f, 0.f, 0.f);
        float4 a2 = make_float4(0.f, 0.f, 0.f, 0.f);
        float4 a3 = make_float4(0.f, 0.f, 0.f, 0.f);
        int e = j0;
        for (; e + 4 <= j1; e += 4) {
            int s0 = eSrc[e], s1 = eSrc[e + 1], s2 = eSrc[e + 2], s3 = eSrc[e + 3];
            bf4_accum(H2[(size_t)s0 * 8 + feat4], a0);
            bf4_accum(H2[(size_t)s1 * 8 + feat4], a1);
            bf4_accum(H2[(size_t)s2 * 8 + feat4], a2);
            bf4_accum(H2[(size_t)s3 * 8 + feat4], a3);
        }
        for (; e < j1; ++e) bf4_accum(H2[(size_t)eSrc[e] * 8 + feat4], a0);
        float4 self = make_float4(0.f, 0.f, 0.f, 0.f);
        bf4_accum(H2[(size_t)node * 8 + feat4], self);
        float dv = dinv[node];
        float4 cb = b4[feat4];
        float4 r;
        r.x = fmaf((a0.x + a1.x) + (a2.x + a3.x) + self.x, dv, cb.x);
        r.y = fmaf((a0.y + a1.y) + (a2.y + a3.y) + self.y, dv, cb.y);
        r.z = fmaf((a0.z + a1.z) + (a2.z + a3.z) + self.z, dv, cb.z);
        r.w = fmaf((a0.w + a1.w) + (a2.w + a3.w) + self.w, dv, cb.w);
        ((float4*)Xs)[(threadIdx.x >> 3) * 8 + feat4] = r;
    }
    __syncthreads();

    // ---- phase B ----
    int rows = min(64, n - r0);
    for (int r = 0; r < rows; ++r) {
        const float* x = Xs + r * 32;
        float a0 = bb.x, a1 = bb.y;
#pragma unroll
        for (int k = 0; k < 32; ++k) {
            float xv = x[k];
            a0 = fmaf(xv, w[k].x, a0);
            a1 = fmaf(xv, w[k].y, a1);
        }
        f32x2 v;
        v.x = a0; v.y = a1;
        __builtin_nontemporal_store(v, (f32x2*)(Y + (size_t)(r0 + r) * 1024 + c0));
    }
}

// ---- launch -------------------------------------------------------------

extern "C" void kernel_launch(void* const* d_in, const int* in_sizes, int n_in,
                              void* d_out, int out_size, void* d_ws, size_t ws_size,
                              hipStream_t stream) {
    const float* z   = (const float*)d_in[0];
    const int*   ei  = (const int*)d_in[1];
    const float* W1  = (const float*)d_in[2];
    const float* b1  = (const float*)d_in[3];
    const float* W2  = (const float*)d_in[4];
    const float* b2  = (const float*)d_in[5];
    const float* Wfc = (const float*)d_in[6];
    const float* bfc = (const float*)d_in[7];
    float* out = (float*)d_out;

    int n = in_sizes[0] / 64;
    int E = in_sizes[1] / 2;
    const int* src = ei;
    const int* dst = ei + E;

    // Workspace (4-byte words):
    //   cnt[nPad] | work[16] | off[n+1 pad4] | slot[Epad] | eSrc[Epad] | dinv[n]
    //   | h1b (n*64 bf16 = n*32 words) | h2b (n*32 bf16 = n*16 words)
    int nPad = (n + 3) & ~3;
    int ePad = (E + 3) & ~3;
    int* cnt    = (int*)d_ws;
    int* work   = cnt + nPad;
    int* off    = work + 16;
    int* slot   = off + ((n + 1 + 3) & ~3);
    int* eSrc   = slot + ePad;
    float* dinv = (float*)(eSrc + ePad);
    unsigned short* h1b = (unsigned short*)(dinv + nPad);           // n*64 bf16
    unsigned short* h2b = (unsigned short*)(dinv + nPad + (size_t)n * 32);  // n*32 bf16

    int nChunks = (n + SCHUNK - 1) / SCHUNK;

    // ---- CSR build + norms ----
    {
        int n4 = (nPad + 16) / 4;  // zero cnt + work together
        k_zero<<<(n4 + TB - 1) / TB, TB, 0, stream>>>((int4*)cnt, n4);
    }
    k_hist<<<(E + TB - 1) / TB, TB, 0, stream>>>(dst, cnt, slot, E);
    k_scanLB<<<nChunks, 1024, 0, stream>>>(cnt, off, dinv, work, n, E);

    // ---- union: CSR fill + conv1 GEMM (bf16 out) ----
    {
        int fillBlocks = (E + TB - 1) / TB;
        int gemmBlocks = (n + 15) / 16;
        k_fill_gemm<<<fillBlocks + gemmBlocks, TB, 0, stream>>>(
            src, dst, off, slot, eSrc, E, fillBlocks, z, W1, dinv, h1b, n);
    }

    // ---- conv1 agg + conv2 GEMM -> h2b ----
    k_agg64g2<<<(n + 15) / 16, TB, 0, stream>>>((const uint2*)h1b, off, eSrc, dinv,
                                                (const float4*)b1, W2, h2b, n);

    // ---- conv2 agg + FC -> out ----
    k_aggfc<<<(n + 63) / 64, FCTB, 0, stream>>>((const uint2*)h2b, off, eSrc, dinv,
                                                (const float4*)b2, Wfc, bfc, out, n);
}